// Round 12
// baseline (314.164 us; speedup 1.0000x reference)
//
#include <hip/hip_runtime.h>

#define B_ 8
#define K_ 4096
#define C_ 128
#define KN 16
#define GR 16
#define CS 0.4375f
#define GLO -3.5f
#define CAP 768

typedef __attribute__((ext_vector_type(8))) short bf16x8;
typedef __attribute__((ext_vector_type(4))) float f32x4;

__device__ __forceinline__ unsigned short f2bf(float f) {
  unsigned u = __float_as_uint(f);
  unsigned r = (u + 0x7FFFu + ((u >> 16) & 1u)) >> 16;
  return (unsigned short)r;
}
__device__ __forceinline__ float bf2f(unsigned short s) {
  return __uint_as_float(((unsigned)s) << 16);
}

__device__ __forceinline__ float dist_exact(float4 q, float4 c) {
  float dot = __fadd_rn(__fadd_rn(__fmul_rn(q.x, c.x), __fmul_rn(q.y, c.y)),
                        __fmul_rn(q.z, c.z));
  return __fadd_rn(__fadd_rn(q.w, c.w), __fmul_rn(-2.0f, dot));
}
// rank-equivalent screen value: e = c.w/2 - q.c  (d = 2e + q.w, monotone)
__device__ __forceinline__ float escr(float4 q, float4 c, float ch) {
  return fmaf(-q.x, c.x, fmaf(-q.y, c.y, fmaf(-q.z, c.z, ch)));
}

// ---------------------------------------------------------------------------
// Kernel 1 (fused pre): lnpos | pack | wcatT | cell-histogram by block range
// ---------------------------------------------------------------------------
__global__ __launch_bounds__(256) void k_pre(
    const float* __restrict__ x, const float* __restrict__ pos,
    const float* __restrict__ gamma, const float* __restrict__ beta,
    const float* __restrict__ Wa1, const float* __restrict__ Wf1,
    const float* __restrict__ coords, unsigned short* __restrict__ A,
    unsigned short* __restrict__ WT, float4* __restrict__ cc4,
    unsigned* __restrict__ counts, int* __restrict__ cellid) {
  int blk = blockIdx.x;
  if (blk < 8192) {
    int wave = threadIdx.x >> 6;
    int lane = threadIdx.x & 63;
    size_t row = (size_t)blk * 4 + wave;
    const float2* xr = (const float2*)(x + row * C_);
    const float2* pr = (const float2*)(pos + row * C_);
    float2 a = xr[lane];
    float s = a.x + a.y;
#pragma unroll
    for (int o = 1; o < 64; o <<= 1) s += __shfl_xor(s, o);
    float mu = s * (1.0f / 128.0f);
    float dx = a.x - mu, dy = a.y - mu;
    float v = dx * dx + dy * dy;
#pragma unroll
    for (int o = 1; o < 64; o <<= 1) v += __shfl_xor(v, o);
    float rstd = rsqrtf(v * (1.0f / 128.0f) + 1e-5f);
    float2 gm = ((const float2*)gamma)[lane];
    float2 bt = ((const float2*)beta)[lane];
    float2 pp = pr[lane];
    float o0 = dx * rstd * gm.x + bt.x + pp.x;
    float o1 = dy * rstd * gm.y + bt.y + pp.y;
    ushort2 o = make_ushort2(f2bf(o0), f2bf(o1));
    *(ushort2*)(A + row * C_ + 2 * lane) = o;
  } else if (blk < 8320) {
    int i = (blk - 8192) * 256 + threadIdx.x;
    float px = coords[i * 3], py = coords[i * 3 + 1], pz = coords[i * 3 + 2];
    float w = __fadd_rn(__fadd_rn(__fmul_rn(px, px), __fmul_rn(py, py)),
                        __fmul_rn(pz, pz));
    cc4[i] = make_float4(px, py, pz, w);
  } else if (blk < 8576) {
    int i = (blk - 8320) * 256 + threadIdx.x;  // 0..65535
    int q = i >> 7;
    int r = i & 127;
    float v;
    if (q < 128)
      v = Wa1[r * 128 + q];
    else if (q < 256)
      v = Wf1[r * 128 + (q - 128)] - Wf1[(128 + r) * 128 + (q - 128)];
    else {
      int c = (q - 256) >> 1;
      if (((q - 256) & 1) == 0)
        v = Wa1[(128 + r) * 128 + c];
      else
        v = Wf1[(128 + r) * 128 + c];
    }
    WT[i] = f2bf(v);
  } else {
    // cell histogram
    int i = (blk - 8576) * 256 + threadIdx.x;  // 0..32767
    float px = coords[i * 3], py = coords[i * 3 + 1], pz = coords[i * 3 + 2];
    int cx = (int)floorf((px - GLO) * (1.0f / CS));
    int cy = (int)floorf((py - GLO) * (1.0f / CS));
    int cz = (int)floorf((pz - GLO) * (1.0f / CS));
    cx = min(15, max(0, cx));
    cy = min(15, max(0, cy));
    cz = min(15, max(0, cz));
    int cid = (cx << 8) | (cy << 4) | cz;
    cellid[i] = cid;
    atomicAdd(&counts[(i >> 12) * 4096 + cid], 1u);
  }
}

// ---------------------------------------------------------------------------
// Kernel 2: per-batch exclusive prefix sum over 4096 cells (8 blocks)
// ---------------------------------------------------------------------------
__global__ __launch_bounds__(1024) void k_scan(const unsigned* __restrict__ counts,
                                               unsigned* __restrict__ start,
                                               unsigned* __restrict__ cursor) {
  __shared__ unsigned ts[1024];
  int b = blockIdx.x, t = threadIdx.x;
  const unsigned* cb = counts + b * 4096;
  unsigned c0 = cb[4 * t], c1 = cb[4 * t + 1], c2 = cb[4 * t + 2],
           c3 = cb[4 * t + 3];
  ts[t] = c0 + c1 + c2 + c3;
  __syncthreads();
  for (int off = 1; off < 1024; off <<= 1) {
    unsigned v = ts[t];
    unsigned u = (t >= off) ? ts[t - off] : 0u;
    __syncthreads();
    ts[t] = v + u;
    __syncthreads();
  }
  unsigned excl = (t == 0) ? 0u : ts[t - 1];
  unsigned base = (unsigned)b * 4096u + excl;
  unsigned g = b * 4096 + 4 * t;
  start[g] = base;
  start[g + 1] = base + c0;
  start[g + 2] = base + c0 + c1;
  start[g + 3] = base + c0 + c1 + c2;
  cursor[g] = base;
  cursor[g + 1] = base + c0;
  cursor[g + 2] = base + c0 + c1;
  cursor[g + 3] = base + c0 + c1 + c2;
}

// ---------------------------------------------------------------------------
// Kernel 3: scatter points into cell-sorted order (stores local idx)
// ---------------------------------------------------------------------------
__global__ __launch_bounds__(256) void k_scatter(
    const float4* __restrict__ cc4, const int* __restrict__ cellid,
    unsigned* __restrict__ cursor, float4* __restrict__ sC,
    int* __restrict__ sI) {
  int i = blockIdx.x * 256 + threadIdx.x;  // 0..32767
  int g = (i >> 12) * 4096 + cellid[i];
  unsigned p = atomicAdd(&cursor[g], 1u);
  sC[p] = cc4[i];
  sI[p] = i & 4095;
}

// ---------------------------------------------------------------------------
// Kernel 4: grid kNN. Block per cell; 27-cell candidates staged in LDS;
// bound->gather->exact lex sort; margin-certified else fallback list.
// ---------------------------------------------------------------------------
__global__ __launch_bounds__(256) void k_knng(
    const float4* __restrict__ sC, const int* __restrict__ sI,
    const unsigned* __restrict__ start, const unsigned* __restrict__ counts,
    int* __restrict__ idx, int* __restrict__ fblist, int* __restrict__ fbcnt) {
  __shared__ float4 candL[CAP];
  __shared__ int sidxL[CAP];
  __shared__ unsigned cbuf[4][4][64];
  __shared__ unsigned scnt[4][4];
  __shared__ int fbbase;
  int bi = blockIdx.x;
  int b = bi >> 12, cid = bi & 4095;
  unsigned nq = counts[bi];
  if (nq == 0) return;
  int cx = cid >> 8, cy = (cid >> 4) & 15, cz = cid & 15;
  int t = threadIdx.x, wave = t >> 6, lane = t & 63;
  unsigned qs = start[bi];

  // ---- stage 27-cell candidates (9 contiguous runs) ----
  int n = 0;
  {
    int zlo = cz > 0 ? cz - 1 : 0;
    int zhi = cz < 15 ? cz + 1 : 15;
    for (int dx = -1; dx <= 1; ++dx) {
      int X = cx + dx;
      if (X < 0 || X > 15) continue;
      for (int dy = -1; dy <= 1; ++dy) {
        int Y = cy + dy;
        if (Y < 0 || Y > 15) continue;
        int glo = b * 4096 + (X << 8) + (Y << 4) + zlo;
        int ghi = glo + (zhi - zlo);
        unsigned rs = start[glo];
        unsigned re = start[ghi] + counts[ghi];
        int len = (int)(re - rs);
        if (n + len <= CAP) {
          for (int i = t; i < len; i += 256) {
            candL[n + i] = sC[rs + i];
            sidxL[n + i] = sI[rs + i];
          }
        }
        n += len;
      }
    }
  }
  if (n > CAP || n < 17) {  // uniform: fallback all queries of this cell
    if (t == 0) fbbase = atomicAdd(fbcnt, (int)nq);
    __syncthreads();
    for (unsigned i = t; i < nq; i += 256)
      fblist[fbbase + i] = b * 4096 + sI[qs + i];
    return;
  }
  __syncthreads();

  int nIter = (n + 63) >> 6;
  unsigned qe = qs + nq;
  float clox = GLO + cx * CS, cloy = GLO + cy * CS, cloz = GLO + cz * CS;

  for (unsigned q0 = qs + wave * 4; q0 < qe; q0 += 16) {
    int nv = (int)(qe - q0);
    if (nv > 4) nv = 4;
    float4 Q[4];
    int orig[4];
#pragma unroll
    for (int qq = 0; qq < 4; ++qq) {
      unsigned qi = q0 + (qq < nv ? (unsigned)qq : 0u);
      Q[qq] = sC[qi];
      orig[qq] = sI[qi];
    }
    // pass A: per-lane min of e (self included; 17th bound covers)
    float mn[4] = {1e30f, 1e30f, 1e30f, 1e30f};
    for (int it = 0; it < nIter; ++it) {
      int j = (it << 6) + lane;
      bool v = j < n;
      float4 c = candL[v ? j : 0];
      float ch = c.w * 0.5f;
#pragma unroll
      for (int qq = 0; qq < 4; ++qq) {
        float e = escr(Q[qq], c, ch);
        if (v) mn[qq] = fminf(mn[qq], e);
      }
    }
    float ub[4];
#pragma unroll
    for (int qq = 0; qq < 4; ++qq) {
      float v = mn[qq];
#pragma unroll
      for (int k = 2; k <= 64; k <<= 1) {
#pragma unroll
        for (int jj = k >> 1; jj >= 1; jj >>= 1) {
          float o = __shfl_xor(v, jj);
          bool amHigh = (lane & jj) != 0;
          bool up = (lane & k) != 0;
          bool gt = v > o;
          bool take = (amHigh ? !gt : gt) ^ up;
          v = take ? o : v;
        }
      }
      ub[qq] = __shfl(v, 16) + 5e-4f;
    }
    if (lane < 4) scnt[wave][lane] = 0u;
    __asm__ volatile("s_waitcnt lgkmcnt(0)" ::: "memory");
    // pass B: gather candidate LDS-slots with e <= ub
    for (int it = 0; it < nIter; ++it) {
      int j = (it << 6) + lane;
      bool v = j < n;
      float4 c = candL[v ? j : 0];
      float ch = c.w * 0.5f;
#pragma unroll
      for (int qq = 0; qq < 4; ++qq) {
        float e = escr(Q[qq], c, ch);
        if (v && qq < nv && e <= ub[qq]) {
          unsigned pos = atomicAdd(&scnt[wave][qq], 1u);
          if (pos < 64u) cbuf[wave][qq][pos] = (unsigned)j;
        }
      }
    }
    __asm__ volatile("s_waitcnt lgkmcnt(0)" ::: "memory");
    // pass C: exact recompute, self-exclude, lex sort, margin-certify
    for (int qq = 0; qq < nv; ++qq) {
      unsigned m = scnt[wave][qq];
      if (m > 64u) {
        if (lane == 0) {
          int p = atomicAdd(fbcnt, 1);
          fblist[p] = b * 4096 + orig[qq];
        }
        continue;
      }
      bool valid = lane < (int)m;
      unsigned ji = valid ? cbuf[wave][qq][lane] : 0u;
      float4 c = candL[ji];
      int io = valid ? sidxL[ji] : 0x7fffffff;
      if (io == orig[qq]) valid = false;
      float dC = valid ? dist_exact(Q[qq], c) : 1e30f;
      int iC = valid ? io : 0x7fffffff;
#pragma unroll
      for (int k = 2; k <= 64; k <<= 1) {
#pragma unroll
        for (int jj = k >> 1; jj >= 1; jj >>= 1) {
          float od = __shfl_xor(dC, jj);
          int oi = __shfl_xor(iC, jj);
          bool amHigh = (lane & jj) != 0;
          bool up = (lane & k) != 0;
          bool gt = (dC > od) || (dC == od && iC > oi);
          bool take = (amHigh ? !gt : gt) ^ up;
          dC = take ? od : dC;
          iC = take ? oi : iC;
        }
      }
      float d16 = __shfl(dC, 15);
      float mg = 1e15f;
      if (cx >= 2) mg = fminf(mg, Q[qq].x - (clox - CS));
      if (cx <= 13) mg = fminf(mg, (clox + 2.0f * CS) - Q[qq].x);
      if (cy >= 2) mg = fminf(mg, Q[qq].y - (cloy - CS));
      if (cy <= 13) mg = fminf(mg, (cloy + 2.0f * CS) - Q[qq].y);
      if (cz >= 2) mg = fminf(mg, Q[qq].z - (cloz - CS));
      if (cz <= 13) mg = fminf(mg, (cloz + 2.0f * CS) - Q[qq].z);
      bool ok = d16 <= mg * mg - 1e-4f;
      if (ok) {
        if (lane < KN)
          idx[((size_t)b * K_ + orig[qq]) * KN + lane] = iC;
      } else if (lane == 0) {
        int p = atomicAdd(fbcnt, 1);
        fblist[p] = b * 4096 + orig[qq];
      }
    }
  }
}

// ---------------------------------------------------------------------------
// Kernel 5: fallback full-scan kNN, one query per wave (R9 machinery)
// ---------------------------------------------------------------------------
__global__ __launch_bounds__(256) void k_fb(const float4* __restrict__ cc4,
                                            const int* __restrict__ fblist,
                                            const int* __restrict__ fbcnt,
                                            int* __restrict__ idx) {
  __shared__ unsigned cbuf[4][64];
  __shared__ unsigned scnt[4];
  int t = threadIdx.x, wave = t >> 6, lane = t & 63;
  int count = *fbcnt;
  for (int w = blockIdx.x * 4 + wave; w < count; w += 2048) {
    int qg = fblist[w];
    int b = qg >> 12, ql = qg & 4095;
    const float4* cb = cc4 + (size_t)b * K_;
    float4 Q = cb[ql];
    float mn = 1e30f;
#pragma unroll 4
    for (int it = 0; it < 64; ++it) {
      float4 c = cb[(it << 6) + lane];
      mn = fminf(mn, escr(Q, c, c.w * 0.5f));
    }
    float v = mn;
#pragma unroll
    for (int k = 2; k <= 64; k <<= 1) {
#pragma unroll
      for (int jj = k >> 1; jj >= 1; jj >>= 1) {
        float o = __shfl_xor(v, jj);
        bool amHigh = (lane & jj) != 0;
        bool up = (lane & k) != 0;
        bool gt = v > o;
        bool take = (amHigh ? !gt : gt) ^ up;
        v = take ? o : v;
      }
    }
    float ub = __shfl(v, 16) + 5e-4f;
    if (lane == 0) scnt[wave] = 0u;
    __asm__ volatile("s_waitcnt lgkmcnt(0)" ::: "memory");
#pragma unroll 2
    for (int it = 0; it < 64; ++it) {
      int j = (it << 6) + lane;
      float4 c = cb[j];
      float e = escr(Q, c, c.w * 0.5f);
      if (e <= ub) {
        unsigned pos = atomicAdd(&scnt[wave], 1u);
        if (pos < 64u) cbuf[wave][pos] = (unsigned)j;
      }
    }
    __asm__ volatile("s_waitcnt lgkmcnt(0)" ::: "memory");
    unsigned m = scnt[wave];
    m = m < 64u ? m : 64u;
    bool valid = lane < (int)m;
    unsigned ji = valid ? cbuf[wave][lane] : 0u;
    if (valid && ji == (unsigned)ql) valid = false;
    float4 c = cb[ji];
    float dC = valid ? dist_exact(Q, c) : 1e30f;
    int iC = valid ? (int)ji : 0x7fffffff;
#pragma unroll
    for (int k = 2; k <= 64; k <<= 1) {
#pragma unroll
      for (int jj = k >> 1; jj >= 1; jj >>= 1) {
        float od = __shfl_xor(dC, jj);
        int oi = __shfl_xor(iC, jj);
        bool amHigh = (lane & jj) != 0;
        bool up = (lane & k) != 0;
        bool gt = (dC > od) || (dC == od && iC > oi);
        bool take = (amHigh ? !gt : gt) ^ up;
        dC = take ? od : dC;
        iC = take ? oi : iC;
      }
    }
    if (lane < KN) idx[((size_t)b * K_ + ql) * KN + lane] = iC;
  }
}

// ---------------------------------------------------------------------------
// Kernel 6: MFMA GEMM  SN_bf16[32768,512] = A_bf16[32768,128] @ WcatT^T
// ---------------------------------------------------------------------------
__global__ __launch_bounds__(256) void k_gemm_mfma(
    const unsigned short* __restrict__ A, const unsigned short* __restrict__ BT,
    unsigned short* __restrict__ SN) {
  __shared__ char lB[32768];
  int bb = blockIdx.x & 7;
  int rest = blockIdx.x >> 3;
  int mbl = rest >> 2, nb = rest & 3;
  int m0 = bb * 4096 + mbl * 128, n0 = nb * 128;
  int t = threadIdx.x;
  {
    const char* src = (const char*)(BT + (size_t)n0 * 128);
#pragma unroll
    for (int i = 0; i < 8; ++i) {
      int byte = (t + i * 256) * 16;
      int n = byte >> 8;
      int sb = byte ^ ((n & 7) << 4);
      *(float4*)(lB + sb) = *(const float4*)(src + byte);
    }
  }
  __syncthreads();
  int wave = t >> 6, lane = t & 63;
  int wr = wave >> 1, wc = wave & 1;
  int lm = lane & 15, lk = lane >> 4;
  f32x4 z = {0.f, 0.f, 0.f, 0.f};
  f32x4 acc00 = z, acc01 = z, acc02 = z, acc03 = z;
  f32x4 acc10 = z, acc11 = z, acc12 = z, acc13 = z;
  f32x4 acc20 = z, acc21 = z, acc22 = z, acc23 = z;
  f32x4 acc30 = z, acc31 = z, acc32 = z, acc33 = z;
  const char* abase =
      (const char*)A + (size_t)(m0 + wr * 64 + lm) * 256 + lk * 16;
#pragma unroll
  for (int ks = 0; ks < 4; ++ks) {
    bf16x8 af[4], bfr[4];
#pragma unroll
    for (int mt = 0; mt < 4; ++mt)
      af[mt] = *(const bf16x8*)(abase + (size_t)mt * 4096 + ks * 64);
#pragma unroll
    for (int nt = 0; nt < 4; ++nt) {
      int n_local = wc * 64 + nt * 16 + lm;
      int byte = n_local * 256 + ks * 64 + lk * 16;
      byte ^= (n_local & 7) << 4;
      bfr[nt] = *(const bf16x8*)(lB + byte);
    }
    acc00 = __builtin_amdgcn_mfma_f32_16x16x32_bf16(af[0], bfr[0], acc00, 0, 0, 0);
    acc01 = __builtin_amdgcn_mfma_f32_16x16x32_bf16(af[0], bfr[1], acc01, 0, 0, 0);
    acc02 = __builtin_amdgcn_mfma_f32_16x16x32_bf16(af[0], bfr[2], acc02, 0, 0, 0);
    acc03 = __builtin_amdgcn_mfma_f32_16x16x32_bf16(af[0], bfr[3], acc03, 0, 0, 0);
    acc10 = __builtin_amdgcn_mfma_f32_16x16x32_bf16(af[1], bfr[0], acc10, 0, 0, 0);
    acc11 = __builtin_amdgcn_mfma_f32_16x16x32_bf16(af[1], bfr[1], acc11, 0, 0, 0);
    acc12 = __builtin_amdgcn_mfma_f32_16x16x32_bf16(af[1], bfr[2], acc12, 0, 0, 0);
    acc13 = __builtin_amdgcn_mfma_f32_16x16x32_bf16(af[1], bfr[3], acc13, 0, 0, 0);
    acc20 = __builtin_amdgcn_mfma_f32_16x16x32_bf16(af[2], bfr[0], acc20, 0, 0, 0);
    acc21 = __builtin_amdgcn_mfma_f32_16x16x32_bf16(af[2], bfr[1], acc21, 0, 0, 0);
    acc22 = __builtin_amdgcn_mfma_f32_16x16x32_bf16(af[2], bfr[2], acc22, 0, 0, 0);
    acc23 = __builtin_amdgcn_mfma_f32_16x16x32_bf16(af[2], bfr[3], acc23, 0, 0, 0);
    acc30 = __builtin_amdgcn_mfma_f32_16x16x32_bf16(af[3], bfr[0], acc30, 0, 0, 0);
    acc31 = __builtin_amdgcn_mfma_f32_16x16x32_bf16(af[3], bfr[1], acc31, 0, 0, 0);
    acc32 = __builtin_amdgcn_mfma_f32_16x16x32_bf16(af[3], bfr[2], acc32, 0, 0, 0);
    acc33 = __builtin_amdgcn_mfma_f32_16x16x32_bf16(af[3], bfr[3], acc33, 0, 0, 0);
  }
  f32x4 accs[4][4] = {{acc00, acc01, acc02, acc03},
                      {acc10, acc11, acc12, acc13},
                      {acc20, acc21, acc22, acc23},
                      {acc30, acc31, acc32, acc33}};
#pragma unroll
  for (int mt = 0; mt < 4; ++mt) {
#pragma unroll
    for (int nt = 0; nt < 4; ++nt) {
#pragma unroll
      for (int r = 0; r < 4; ++r) {
        int row = m0 + wr * 64 + mt * 16 + lk * 4 + r;
        int col = n0 + wc * 64 + nt * 16 + lm;
        SN[(size_t)row * 512 + col] = f2bf(accs[mt][nt][r]);
      }
    }
  }
}

// ---------------------------------------------------------------------------
// Kernel 7: attention aggregate (R9, unchanged)
// ---------------------------------------------------------------------------
__global__ __launch_bounds__(256) void k_attn(
    const unsigned short* __restrict__ SN, const int* __restrict__ idx,
    const float* __restrict__ b_a1, const float* __restrict__ b_f1,
    const float* __restrict__ W_a2, const float* __restrict__ b_a2,
    float* __restrict__ out) {
  int wave = threadIdx.x >> 6, lane = threadIdx.x & 63;
  int g = lane >> 4, r = lane & 15;
  int b = blockIdx.x & 7;
  int w = blockIdx.x >> 3;  // 0..1023
  size_t gpt = (size_t)b * K_ + w * 4 + wave;
  const unsigned short* sr = SN + gpt * 512;
  bf16x8 sa8 = *(const bf16x8*)(sr + 8 * r);
  bf16x8 sf8 = *(const bf16x8*)(sr + 128 + 8 * r);
  float4 bav0 = *(const float4*)(b_a1 + 8 * r);
  float4 bav1 = *(const float4*)(b_a1 + 8 * r + 4);
  float4 bfv0 = *(const float4*)(b_f1 + 8 * r);
  float4 bfv1 = *(const float4*)(b_f1 + 8 * r + 4);
  float4 w2v0 = *(const float4*)(W_a2 + 8 * r);
  float4 w2v1 = *(const float4*)(W_a2 + 8 * r + 4);
  float sab[8], sfb[8], w2v[8];
  {
    float bav[8] = {bav0.x, bav0.y, bav0.z, bav0.w, bav1.x, bav1.y, bav1.z, bav1.w};
    float bfv[8] = {bfv0.x, bfv0.y, bfv0.z, bfv0.w, bfv1.x, bfv1.y, bfv1.z, bfv1.w};
    float wv[8] = {w2v0.x, w2v0.y, w2v0.z, w2v0.w, w2v1.x, w2v1.y, w2v1.z, w2v1.w};
#pragma unroll
    for (int i = 0; i < 8; ++i) {
      sab[i] = bf2f((unsigned short)sa8[i]) + bav[i];
      sfb[i] = bf2f((unsigned short)sf8[i]) + bfv[i];
      w2v[i] = wv[i];
    }
  }
  float ba2v = b_a2[0];
  int nv = 0;
  if (lane < 16) nv = idx[gpt * 16 + lane];
  float lgl[4];
  float tsv[4][8];
#pragma unroll
  for (int round = 0; round < 4; ++round) {
    int n = __shfl(nv, round * 4 + g);
    const unsigned short* nr =
        SN + ((size_t)b * K_ + n) * 512 + 256 + 16 * r;
    bf16x8 u0 = *(const bf16x8*)(nr);
    bf16x8 u1 = *(const bf16x8*)(nr + 8);
    float dot = 0.0f;
#pragma unroll
    for (int i = 0; i < 4; ++i) {
      float h = sab[i] + bf2f((unsigned short)u0[2 * i]);
      h = h >= 0.0f ? h : 0.2f * h;
      float tv = sfb[i] + bf2f((unsigned short)u0[2 * i + 1]);
      tv = tv >= 0.0f ? tv : 0.2f * tv;
      dot = fmaf(h, w2v[i], dot);
      tsv[round][i] = tv;
    }
#pragma unroll
    for (int i = 0; i < 4; ++i) {
      float h = sab[4 + i] + bf2f((unsigned short)u1[2 * i]);
      h = h >= 0.0f ? h : 0.2f * h;
      float tv = sfb[4 + i] + bf2f((unsigned short)u1[2 * i + 1]);
      tv = tv >= 0.0f ? tv : 0.2f * tv;
      dot = fmaf(h, w2v[4 + i], dot);
      tsv[round][4 + i] = tv;
    }
#pragma unroll
    for (int o = 1; o < 16; o <<= 1) dot += __shfl_xor(dot, o);
    lgl[round] = dot + ba2v;
  }
  float mx = fmaxf(fmaxf(lgl[0], lgl[1]), fmaxf(lgl[2], lgl[3]));
  mx = fmaxf(mx, __shfl_xor(mx, 16));
  mx = fmaxf(mx, __shfl_xor(mx, 32));
  float e[4];
  float s = 0.0f;
#pragma unroll
  for (int round = 0; round < 4; ++round) {
    e[round] = expf(lgl[round] - mx);
    s += e[round];
  }
  s += __shfl_xor(s, 16);
  s += __shfl_xor(s, 32);
  float inv = 1.0f / s;
  float o8[8] = {0, 0, 0, 0, 0, 0, 0, 0};
#pragma unroll
  for (int round = 0; round < 4; ++round) {
    float a = e[round] * inv;
#pragma unroll
    for (int i = 0; i < 8; ++i) o8[i] = fmaf(a, tsv[round][i], o8[i]);
  }
#pragma unroll
  for (int i = 0; i < 8; ++i) {
    o8[i] += __shfl_xor(o8[i], 16);
    o8[i] += __shfl_xor(o8[i], 32);
  }
  if (g == 0) {
    float* op = out + gpt * 128 + 8 * r;
    *(float4*)op = make_float4(o8[0], o8[1], o8[2], o8[3]);
    *(float4*)(op + 4) = make_float4(o8[4], o8[5], o8[6], o8[7]);
  }
}

// ---------------------------------------------------------------------------
extern "C" void kernel_launch(void* const* d_in, const int* in_sizes, int n_in,
                              void* d_out, int out_size, void* d_ws,
                              size_t ws_size, hipStream_t stream) {
  const float* x = (const float*)d_in[0];
  const float* pos = (const float*)d_in[1];
  const float* coords = (const float*)d_in[2];
  const float* gamma = (const float*)d_in[3];
  const float* beta = (const float*)d_in[4];
  const float* Wa1 = (const float*)d_in[5];
  const float* ba1 = (const float*)d_in[6];
  const float* Wa2 = (const float*)d_in[7];
  const float* ba2 = (const float*)d_in[8];
  const float* Wf1 = (const float*)d_in[9];
  const float* bf1 = (const float*)d_in[10];
  float* out = (float*)d_out;

  char* ws = (char*)d_ws;
  const size_t MB = 1024 * 1024;
  unsigned short* A = (unsigned short*)ws;                    // [0,8MB)
  // grid-build arrays live in [8MB,16MB)
  unsigned* counts = (unsigned*)(ws + 8 * MB);                // 128KB
  int* cellid = (int*)(ws + 8 * MB + 128 * 1024);             // 128KB
  unsigned* start = (unsigned*)(ws + 8 * MB + 256 * 1024);    // 128KB
  unsigned* cursor = (unsigned*)(ws + 8 * MB + 384 * 1024);   // 128KB
  float4* sC = (float4*)(ws + 8 * MB + 512 * 1024);           // 512KB
  int* sI = (int*)(ws + 8 * MB + 1024 * 1024);                // 128KB
  int* fblist = (int*)(ws + 8 * MB + 1152 * 1024);            // 128KB
  int* fbcnt = (int*)(ws + 8 * MB + 1280 * 1024);             // 4B
  unsigned short* SN = (unsigned short*)(ws + 16 * MB);       // 32MB
  unsigned short* WT = (unsigned short*)(ws + 80 * MB);       // 128KB
  int* idx = (int*)(ws + 80 * MB + 512 * 1024);               // 2MB
  float4* cc4 = (float4*)(ws + 80 * MB + 2560 * 1024);        // 512KB

  hipMemsetAsync(counts, 0, 32768 * sizeof(unsigned), stream);
  hipMemsetAsync(fbcnt, 0, sizeof(int), stream);
  k_pre<<<8704, 256, 0, stream>>>(x, pos, gamma, beta, Wa1, Wf1, coords, A, WT,
                                  cc4, counts, cellid);
  k_scan<<<8, 1024, 0, stream>>>(counts, start, cursor);
  k_scatter<<<128, 256, 0, stream>>>(cc4, cellid, cursor, sC, sI);
  k_knng<<<32768, 256, 0, stream>>>(sC, sI, start, counts, idx, fblist, fbcnt);
  k_fb<<<512, 256, 0, stream>>>(cc4, fblist, fbcnt, idx);
  k_gemm_mfma<<<1024, 256, 0, stream>>>(A, WT, SN);
  k_attn<<<8192, 256, 0, stream>>>(SN, idx, ba1, bf1, Wa2, ba2, out);
}

// Round 13
// 114.549 us; speedup vs baseline: 2.7426x; 2.7426x over previous
//
#include <hip/hip_runtime.h>

#define B_ 8
#define K_ 4096
#define C_ 128
#define KN 16

typedef __attribute__((ext_vector_type(8))) short bf16x8;
typedef __attribute__((ext_vector_type(4))) float f32x4;

__device__ __forceinline__ unsigned short f2bf(float f) {
  unsigned u = __float_as_uint(f);
  unsigned r = (u + 0x7FFFu + ((u >> 16) & 1u)) >> 16;
  return (unsigned short)r;
}
__device__ __forceinline__ float bf2f(unsigned short s) {
  return __uint_as_float(((unsigned)s) << 16);
}

__device__ __forceinline__ float dist_exact(float4 q, float4 c) {
  float dot = __fadd_rn(__fadd_rn(__fmul_rn(q.x, c.x), __fmul_rn(q.y, c.y)),
                        __fmul_rn(q.z, c.z));
  return __fadd_rn(__fadd_rn(q.w, c.w), __fmul_rn(-2.0f, dot));
}
// doubled rank-equivalent screen: e2 = c.w - 2 q.c  (= 2e, monotone in d)
__device__ __forceinline__ float escr2(float qx2, float qy2, float qz2,
                                       float4 c) {
  return fmaf(-qx2, c.x, fmaf(-qy2, c.y, fmaf(-qz2, c.z, c.w)));
}

// ---------------------------------------------------------------------------
// Kernel 1 (fused pre): lnpos | pack | wcatT by block range
// WT col layout: [0:128]=S_a, [128:256]=S_f, [256:512] interleaved
// (256+2c = N_a[c], 257+2c = N_f[c]).
// ---------------------------------------------------------------------------
__global__ __launch_bounds__(256) void k_pre(
    const float* __restrict__ x, const float* __restrict__ pos,
    const float* __restrict__ gamma, const float* __restrict__ beta,
    const float* __restrict__ Wa1, const float* __restrict__ Wf1,
    const float* __restrict__ coords, unsigned short* __restrict__ A,
    unsigned short* __restrict__ WT, float4* __restrict__ cc4) {
  int blk = blockIdx.x;
  if (blk < 8192) {
    int wave = threadIdx.x >> 6;
    int lane = threadIdx.x & 63;
    size_t row = (size_t)blk * 4 + wave;
    const float2* xr = (const float2*)(x + row * C_);
    const float2* pr = (const float2*)(pos + row * C_);
    float2 a = xr[lane];
    float s = a.x + a.y;
#pragma unroll
    for (int o = 1; o < 64; o <<= 1) s += __shfl_xor(s, o);
    float mu = s * (1.0f / 128.0f);
    float dx = a.x - mu, dy = a.y - mu;
    float v = dx * dx + dy * dy;
#pragma unroll
    for (int o = 1; o < 64; o <<= 1) v += __shfl_xor(v, o);
    float rstd = rsqrtf(v * (1.0f / 128.0f) + 1e-5f);
    float2 gm = ((const float2*)gamma)[lane];
    float2 bt = ((const float2*)beta)[lane];
    float2 pp = pr[lane];
    float o0 = dx * rstd * gm.x + bt.x + pp.x;
    float o1 = dy * rstd * gm.y + bt.y + pp.y;
    ushort2 o = make_ushort2(f2bf(o0), f2bf(o1));
    *(ushort2*)(A + row * C_ + 2 * lane) = o;
  } else if (blk < 8320) {
    int i = (blk - 8192) * 256 + threadIdx.x;
    float px = coords[i * 3], py = coords[i * 3 + 1], pz = coords[i * 3 + 2];
    float w = __fadd_rn(__fadd_rn(__fmul_rn(px, px), __fmul_rn(py, py)),
                        __fmul_rn(pz, pz));
    cc4[i] = make_float4(px, py, pz, w);
  } else {
    int i = (blk - 8320) * 256 + threadIdx.x;  // 0..65535
    int q = i >> 7;
    int r = i & 127;
    float v;
    if (q < 128)
      v = Wa1[r * 128 + q];
    else if (q < 256)
      v = Wf1[r * 128 + (q - 128)] - Wf1[(128 + r) * 128 + (q - 128)];
    else {
      int c = (q - 256) >> 1;
      if (((q - 256) & 1) == 0)
        v = Wa1[(128 + r) * 128 + c];
      else
        v = Wf1[(128 + r) * 128 + c];
    }
    WT[i] = f2bf(v);
  }
}

// ---------------------------------------------------------------------------
// Kernel 2: exact kNN, wave per 4 queries (R9 structure). Pass A screens
// candidates 0..3071 with e2 for the 17th-smallest lane-min bound; pass B
// gathers e2 <= ub over all 4096; pass C recomputes reference-exact bits,
// excludes self, lex-sorts (adaptive 32/64-lane). Selected set == reference.
// ---------------------------------------------------------------------------
__global__ __launch_bounds__(256, 8) void k_knn(const float4* __restrict__ cc4,
                                                int* __restrict__ idx) {
  __shared__ unsigned cbuf[4][4][64];
  __shared__ unsigned scnt[4][4];
  int wave = threadIdx.x >> 6, lane = threadIdx.x & 63;
  int gw = blockIdx.x * 4 + wave;  // 0..8191
  int b = gw >> 10;
  int qbase = (gw & 1023) * 4;
  const float4* cb = cc4 + (size_t)b * K_;
  if (lane < 4) scnt[wave][lane] = 0u;
  __asm__ volatile("s_waitcnt lgkmcnt(0)" ::: "memory");
  float4 Q[4];
  float qx2[4], qy2[4], qz2[4];
#pragma unroll
  for (int qq = 0; qq < 4; ++qq) {
    Q[qq] = cb[qbase + qq];
    qx2[qq] = 2.0f * Q[qq].x;
    qy2[qq] = 2.0f * Q[qq].y;
    qz2[qq] = 2.0f * Q[qq].z;
  }

  // ---- pass A: per-lane min of e2 over 48-candidate slice (3072 total) ----
  float m0 = 1e30f, m1 = 1e30f, m2 = 1e30f, m3 = 1e30f;
#pragma unroll 8
  for (int it = 0; it < 48; ++it) {
    float4 c = cb[(it << 6) + lane];
    m0 = fminf(m0, escr2(qx2[0], qy2[0], qz2[0], c));
    m1 = fminf(m1, escr2(qx2[1], qy2[1], qz2[1], c));
    m2 = fminf(m2, escr2(qx2[2], qy2[2], qz2[2], c));
    m3 = fminf(m3, escr2(qx2[3], qy2[3], qz2[3], c));
  }
  // ---- bound = 17th smallest lane-min + slack (e2-space) ----
  float ub[4];
  float mv[4] = {m0, m1, m2, m3};
#pragma unroll
  for (int qq = 0; qq < 4; ++qq) {
    float v = mv[qq];
#pragma unroll
    for (int k = 2; k <= 64; k <<= 1) {
#pragma unroll
      for (int jj = k >> 1; jj >= 1; jj >>= 1) {
        float o = __shfl_xor(v, jj);
        bool amHigh = (lane & jj) != 0;
        bool up = (lane & k) != 0;
        bool gt = v > o;
        bool take = (amHigh ? !gt : gt) ^ up;
        v = take ? o : v;
      }
    }
    ub[qq] = __shfl(v, 16) + 1e-3f;
  }

  // ---- pass B: gather indices with e2 <= ub (self gathered, excl in C) ----
#pragma unroll 4
  for (int it = 0; it < 64; ++it) {
    int j = (it << 6) + lane;
    float4 c = cb[j];
#pragma unroll
    for (int qq = 0; qq < 4; ++qq) {
      float e = escr2(qx2[qq], qy2[qq], qz2[qq], c);
      if (e <= ub[qq]) {
        unsigned pos = atomicAdd(&scnt[wave][qq], 1u);
        if (pos < 64u) cbuf[wave][qq][pos] = (unsigned)j;
      }
    }
  }
  __asm__ volatile("s_waitcnt lgkmcnt(0)" ::: "memory");

  // ---- pass C: exact recompute, self-exclude, lex sort (adaptive) ----
#pragma unroll
  for (int qq = 0; qq < 4; ++qq) {
    unsigned m = scnt[wave][qq];
    m = m < 64u ? m : 64u;
    bool valid = lane < (int)m;
    unsigned ji = valid ? cbuf[wave][qq][lane] : 0u;
    if (valid && ji == (unsigned)(qbase + qq)) valid = false;
    float4 c = cb[ji];
    float dC = valid ? dist_exact(Q[qq], c) : 1e30f;
    int iC = valid ? (int)ji : 0x7fffffff;
#define SORT_STAGE(KV)                                              \
  {                                                                 \
    const int k = (KV);                                             \
    for (int jj = k >> 1; jj >= 1; jj >>= 1) {                      \
      float od = __shfl_xor(dC, jj);                                \
      int oi = __shfl_xor(iC, jj);                                  \
      bool amHigh = (lane & jj) != 0;                               \
      bool up = (lane & k) != 0;                                    \
      bool gt = (dC > od) || (dC == od && iC > oi);                 \
      bool take = (amHigh ? !gt : gt) ^ up;                         \
      dC = take ? od : dC;                                          \
      iC = take ? oi : iC;                                          \
    }                                                               \
  }
    if (m <= 32u) {
      SORT_STAGE(2) SORT_STAGE(4) SORT_STAGE(8) SORT_STAGE(16) SORT_STAGE(32)
    } else {
      SORT_STAGE(2) SORT_STAGE(4) SORT_STAGE(8) SORT_STAGE(16) SORT_STAGE(32)
      SORT_STAGE(64)
    }
#undef SORT_STAGE
    if (lane < KN)
      idx[((size_t)b * K_ + (qbase + qq)) * KN + lane] = iC;
  }
}

// ---------------------------------------------------------------------------
// Kernel 3: MFMA GEMM  SN_bf16[32768,512] = A_bf16[32768,128] @ WcatT^T
// 128x128 tile, 4 waves. batch = blockIdx&7 -> batch b L2-resident on XCD b.
// ---------------------------------------------------------------------------
__global__ __launch_bounds__(256) void k_gemm_mfma(
    const unsigned short* __restrict__ A, const unsigned short* __restrict__ BT,
    unsigned short* __restrict__ SN) {
  __shared__ char lB[32768];
  int bb = blockIdx.x & 7;
  int rest = blockIdx.x >> 3;
  int mbl = rest >> 2, nb = rest & 3;
  int m0 = bb * 4096 + mbl * 128, n0 = nb * 128;
  int t = threadIdx.x;
  {
    const char* src = (const char*)(BT + (size_t)n0 * 128);
#pragma unroll
    for (int i = 0; i < 8; ++i) {
      int byte = (t + i * 256) * 16;
      int n = byte >> 8;
      int sb = byte ^ ((n & 7) << 4);
      *(float4*)(lB + sb) = *(const float4*)(src + byte);
    }
  }
  __syncthreads();
  int wave = t >> 6, lane = t & 63;
  int wr = wave >> 1, wc = wave & 1;
  int lm = lane & 15, lk = lane >> 4;
  f32x4 z = {0.f, 0.f, 0.f, 0.f};
  f32x4 acc00 = z, acc01 = z, acc02 = z, acc03 = z;
  f32x4 acc10 = z, acc11 = z, acc12 = z, acc13 = z;
  f32x4 acc20 = z, acc21 = z, acc22 = z, acc23 = z;
  f32x4 acc30 = z, acc31 = z, acc32 = z, acc33 = z;
  const char* abase =
      (const char*)A + (size_t)(m0 + wr * 64 + lm) * 256 + lk * 16;
#pragma unroll
  for (int ks = 0; ks < 4; ++ks) {
    bf16x8 af[4], bfr[4];
#pragma unroll
    for (int mt = 0; mt < 4; ++mt)
      af[mt] = *(const bf16x8*)(abase + (size_t)mt * 4096 + ks * 64);
#pragma unroll
    for (int nt = 0; nt < 4; ++nt) {
      int n_local = wc * 64 + nt * 16 + lm;
      int byte = n_local * 256 + ks * 64 + lk * 16;
      byte ^= (n_local & 7) << 4;
      bfr[nt] = *(const bf16x8*)(lB + byte);
    }
    acc00 = __builtin_amdgcn_mfma_f32_16x16x32_bf16(af[0], bfr[0], acc00, 0, 0, 0);
    acc01 = __builtin_amdgcn_mfma_f32_16x16x32_bf16(af[0], bfr[1], acc01, 0, 0, 0);
    acc02 = __builtin_amdgcn_mfma_f32_16x16x32_bf16(af[0], bfr[2], acc02, 0, 0, 0);
    acc03 = __builtin_amdgcn_mfma_f32_16x16x32_bf16(af[0], bfr[3], acc03, 0, 0, 0);
    acc10 = __builtin_amdgcn_mfma_f32_16x16x32_bf16(af[1], bfr[0], acc10, 0, 0, 0);
    acc11 = __builtin_amdgcn_mfma_f32_16x16x32_bf16(af[1], bfr[1], acc11, 0, 0, 0);
    acc12 = __builtin_amdgcn_mfma_f32_16x16x32_bf16(af[1], bfr[2], acc12, 0, 0, 0);
    acc13 = __builtin_amdgcn_mfma_f32_16x16x32_bf16(af[1], bfr[3], acc13, 0, 0, 0);
    acc20 = __builtin_amdgcn_mfma_f32_16x16x32_bf16(af[2], bfr[0], acc20, 0, 0, 0);
    acc21 = __builtin_amdgcn_mfma_f32_16x16x32_bf16(af[2], bfr[1], acc21, 0, 0, 0);
    acc22 = __builtin_amdgcn_mfma_f32_16x16x32_bf16(af[2], bfr[2], acc22, 0, 0, 0);
    acc23 = __builtin_amdgcn_mfma_f32_16x16x32_bf16(af[2], bfr[3], acc23, 0, 0, 0);
    acc30 = __builtin_amdgcn_mfma_f32_16x16x32_bf16(af[3], bfr[0], acc30, 0, 0, 0);
    acc31 = __builtin_amdgcn_mfma_f32_16x16x32_bf16(af[3], bfr[1], acc31, 0, 0, 0);
    acc32 = __builtin_amdgcn_mfma_f32_16x16x32_bf16(af[3], bfr[2], acc32, 0, 0, 0);
    acc33 = __builtin_amdgcn_mfma_f32_16x16x32_bf16(af[3], bfr[3], acc33, 0, 0, 0);
  }
  f32x4 accs[4][4] = {{acc00, acc01, acc02, acc03},
                      {acc10, acc11, acc12, acc13},
                      {acc20, acc21, acc22, acc23},
                      {acc30, acc31, acc32, acc33}};
#pragma unroll
  for (int mt = 0; mt < 4; ++mt) {
#pragma unroll
    for (int nt = 0; nt < 4; ++nt) {
#pragma unroll
      for (int r = 0; r < 4; ++r) {
        int row = m0 + wr * 64 + mt * 16 + lk * 4 + r;
        int col = n0 + wc * 64 + nt * 16 + lm;
        SN[(size_t)row * 512 + col] = f2bf(accs[mt][nt][r]);
      }
    }
  }
}

// ---------------------------------------------------------------------------
// Kernel 4: attention aggregate. Wave per point; lane (g=lane>>4, r=lane&15)
// handles channels [8r,8r+8) of neighbors {g,4+g,8+g,12+g}.
// ---------------------------------------------------------------------------
__global__ __launch_bounds__(256) void k_attn(
    const unsigned short* __restrict__ SN, const int* __restrict__ idx,
    const float* __restrict__ b_a1, const float* __restrict__ b_f1,
    const float* __restrict__ W_a2, const float* __restrict__ b_a2,
    float* __restrict__ out) {
  int wave = threadIdx.x >> 6, lane = threadIdx.x & 63;
  int g = lane >> 4, r = lane & 15;
  int b = blockIdx.x & 7;
  int w = blockIdx.x >> 3;  // 0..1023
  size_t gpt = (size_t)b * K_ + w * 4 + wave;
  const unsigned short* sr = SN + gpt * 512;
  bf16x8 sa8 = *(const bf16x8*)(sr + 8 * r);
  bf16x8 sf8 = *(const bf16x8*)(sr + 128 + 8 * r);
  float4 bav0 = *(const float4*)(b_a1 + 8 * r);
  float4 bav1 = *(const float4*)(b_a1 + 8 * r + 4);
  float4 bfv0 = *(const float4*)(b_f1 + 8 * r);
  float4 bfv1 = *(const float4*)(b_f1 + 8 * r + 4);
  float4 w2v0 = *(const float4*)(W_a2 + 8 * r);
  float4 w2v1 = *(const float4*)(W_a2 + 8 * r + 4);
  float sab[8], sfb[8], w2v[8];
  {
    float bav[8] = {bav0.x, bav0.y, bav0.z, bav0.w, bav1.x, bav1.y, bav1.z, bav1.w};
    float bfv[8] = {bfv0.x, bfv0.y, bfv0.z, bfv0.w, bfv1.x, bfv1.y, bfv1.z, bfv1.w};
    float wv[8] = {w2v0.x, w2v0.y, w2v0.z, w2v0.w, w2v1.x, w2v1.y, w2v1.z, w2v1.w};
#pragma unroll
    for (int i = 0; i < 8; ++i) {
      sab[i] = bf2f((unsigned short)sa8[i]) + bav[i];
      sfb[i] = bf2f((unsigned short)sf8[i]) + bfv[i];
      w2v[i] = wv[i];
    }
  }
  float ba2v = b_a2[0];
  int nv = 0;
  if (lane < 16) nv = idx[gpt * 16 + lane];
  float lgl[4];
  float tsv[4][8];
#pragma unroll
  for (int round = 0; round < 4; ++round) {
    int n = __shfl(nv, round * 4 + g);
    const unsigned short* nr =
        SN + ((size_t)b * K_ + n) * 512 + 256 + 16 * r;
    bf16x8 u0 = *(const bf16x8*)(nr);
    bf16x8 u1 = *(const bf16x8*)(nr + 8);
    float dot = 0.0f;
#pragma unroll
    for (int i = 0; i < 4; ++i) {
      float h = sab[i] + bf2f((unsigned short)u0[2 * i]);
      h = h >= 0.0f ? h : 0.2f * h;
      float tv = sfb[i] + bf2f((unsigned short)u0[2 * i + 1]);
      tv = tv >= 0.0f ? tv : 0.2f * tv;
      dot = fmaf(h, w2v[i], dot);
      tsv[round][i] = tv;
    }
#pragma unroll
    for (int i = 0; i < 4; ++i) {
      float h = sab[4 + i] + bf2f((unsigned short)u1[2 * i]);
      h = h >= 0.0f ? h : 0.2f * h;
      float tv = sfb[4 + i] + bf2f((unsigned short)u1[2 * i + 1]);
      tv = tv >= 0.0f ? tv : 0.2f * tv;
      dot = fmaf(h, w2v[4 + i], dot);
      tsv[round][4 + i] = tv;
    }
#pragma unroll
    for (int o = 1; o < 16; o <<= 1) dot += __shfl_xor(dot, o);
    lgl[round] = dot + ba2v;
  }
  float mx = fmaxf(fmaxf(lgl[0], lgl[1]), fmaxf(lgl[2], lgl[3]));
  mx = fmaxf(mx, __shfl_xor(mx, 16));
  mx = fmaxf(mx, __shfl_xor(mx, 32));
  float e[4];
  float s = 0.0f;
#pragma unroll
  for (int round = 0; round < 4; ++round) {
    e[round] = expf(lgl[round] - mx);
    s += e[round];
  }
  s += __shfl_xor(s, 16);
  s += __shfl_xor(s, 32);
  float inv = 1.0f / s;
  float o8[8] = {0, 0, 0, 0, 0, 0, 0, 0};
#pragma unroll
  for (int round = 0; round < 4; ++round) {
    float a = e[round] * inv;
#pragma unroll
    for (int i = 0; i < 8; ++i) o8[i] = fmaf(a, tsv[round][i], o8[i]);
  }
#pragma unroll
  for (int i = 0; i < 8; ++i) {
    o8[i] += __shfl_xor(o8[i], 16);
    o8[i] += __shfl_xor(o8[i], 32);
  }
  if (g == 0) {
    float* op = out + gpt * 128 + 8 * r;
    *(float4*)op = make_float4(o8[0], o8[1], o8[2], o8[3]);
    *(float4*)(op + 4) = make_float4(o8[4], o8[5], o8[6], o8[7]);
  }
}

// ---------------------------------------------------------------------------
extern "C" void kernel_launch(void* const* d_in, const int* in_sizes, int n_in,
                              void* d_out, int out_size, void* d_ws,
                              size_t ws_size, hipStream_t stream) {
  const float* x = (const float*)d_in[0];
  const float* pos = (const float*)d_in[1];
  const float* coords = (const float*)d_in[2];
  const float* gamma = (const float*)d_in[3];
  const float* beta = (const float*)d_in[4];
  const float* Wa1 = (const float*)d_in[5];
  const float* ba1 = (const float*)d_in[6];
  const float* Wa2 = (const float*)d_in[7];
  const float* ba2 = (const float*)d_in[8];
  const float* Wf1 = (const float*)d_in[9];
  const float* bf1 = (const float*)d_in[10];
  float* out = (float*)d_out;

  char* ws = (char*)d_ws;
  unsigned short* A = (unsigned short*)ws;                                // 8MB
  unsigned short* SN = (unsigned short*)(ws + (size_t)16 * 1024 * 1024);  // 32MB
  unsigned short* WT = (unsigned short*)(ws + (size_t)80 * 1024 * 1024);  // 128KB
  int* idx = (int*)(ws + (size_t)80 * 1024 * 1024 + 512 * 1024);          // 2MB
  float4* cc4 = (float4*)(ws + (size_t)80 * 1024 * 1024 + 2560 * 1024);   // 512KB

  k_pre<<<8576, 256, 0, stream>>>(x, pos, gamma, beta, Wa1, Wf1, coords, A, WT,
                                  cc4);
  k_knn<<<2048, 256, 0, stream>>>(cc4, idx);
  k_gemm_mfma<<<1024, 256, 0, stream>>>(A, WT, SN);
  k_attn<<<8192, 256, 0, stream>>>(SN, idx, ba1, bf1, Wa2, ba2, out);
}

// Round 14
// 111.220 us; speedup vs baseline: 2.8247x; 1.0299x over previous
//
#include <hip/hip_runtime.h>

#define B_ 8
#define K_ 4096
#define C_ 128
#define KN 16

typedef __attribute__((ext_vector_type(8))) short bf16x8;
typedef __attribute__((ext_vector_type(4))) float f32x4;

__device__ __forceinline__ unsigned short f2bf(float f) {
  unsigned u = __float_as_uint(f);
  unsigned r = (u + 0x7FFFu + ((u >> 16) & 1u)) >> 16;
  return (unsigned short)r;
}
__device__ __forceinline__ float bf2f(unsigned short s) {
  return __uint_as_float(((unsigned)s) << 16);
}

__device__ __forceinline__ float dist_exact(float4 q, float4 c) {
  float dot = __fadd_rn(__fadd_rn(__fmul_rn(q.x, c.x), __fmul_rn(q.y, c.y)),
                        __fmul_rn(q.z, c.z));
  return __fadd_rn(__fadd_rn(q.w, c.w), __fmul_rn(-2.0f, dot));
}
// doubled rank-equivalent screen: e2 = c.w - 2 q.c  (= 2e, monotone in d)
__device__ __forceinline__ float escr2(float qx2, float qy2, float qz2,
                                       float4 c) {
  return fmaf(-qx2, c.x, fmaf(-qy2, c.y, fmaf(-qz2, c.z, c.w)));
}

// ---------------------------------------------------------------------------
// Kernel 1 (fused pre): lnpos (float4, 2 rows/wave) | pack | wcatT
// WT col layout: [0:128]=S_a, [128:256]=S_f, [256:512] interleaved
// (256+2c = N_a[c], 257+2c = N_f[c]).
// ---------------------------------------------------------------------------
__global__ __launch_bounds__(256) void k_pre(
    const float* __restrict__ x, const float* __restrict__ pos,
    const float* __restrict__ gamma, const float* __restrict__ beta,
    const float* __restrict__ Wa1, const float* __restrict__ Wf1,
    const float* __restrict__ coords, unsigned short* __restrict__ A,
    unsigned short* __restrict__ WT, float4* __restrict__ cc4) {
  int blk = blockIdx.x;
  if (blk < 4096) {
    // LayerNorm + pos: wave handles 2 rows; lane l -> row (l>>5), chans 4*(l&31)
    int wave = threadIdx.x >> 6;
    int lane = threadIdx.x & 63;
    int l32 = lane & 31;
    size_t row = (size_t)blk * 8 + wave * 2 + (lane >> 5);
    float4 a = ((const float4*)(x + row * C_))[l32];
    float s = (a.x + a.y) + (a.z + a.w);
#pragma unroll
    for (int o = 1; o < 32; o <<= 1) s += __shfl_xor(s, o);
    float mu = s * (1.0f / 128.0f);
    float d0 = a.x - mu, d1 = a.y - mu, d2 = a.z - mu, d3 = a.w - mu;
    float v = (d0 * d0 + d1 * d1) + (d2 * d2 + d3 * d3);
#pragma unroll
    for (int o = 1; o < 32; o <<= 1) v += __shfl_xor(v, o);
    float rstd = rsqrtf(v * (1.0f / 128.0f) + 1e-5f);
    float4 gm = ((const float4*)gamma)[l32];
    float4 bt = ((const float4*)beta)[l32];
    float4 pp = ((const float4*)(pos + row * C_))[l32];
    float o0 = d0 * rstd * gm.x + bt.x + pp.x;
    float o1 = d1 * rstd * gm.y + bt.y + pp.y;
    float o2 = d2 * rstd * gm.z + bt.z + pp.z;
    float o3 = d3 * rstd * gm.w + bt.w + pp.w;
    ushort4 o = make_ushort4(f2bf(o0), f2bf(o1), f2bf(o2), f2bf(o3));
    *(ushort4*)(A + row * C_ + 4 * l32) = o;
  } else if (blk < 4224) {
    int i = (blk - 4096) * 256 + threadIdx.x;
    float px = coords[i * 3], py = coords[i * 3 + 1], pz = coords[i * 3 + 2];
    float w = __fadd_rn(__fadd_rn(__fmul_rn(px, px), __fmul_rn(py, py)),
                        __fmul_rn(pz, pz));
    cc4[i] = make_float4(px, py, pz, w);
  } else {
    int i = (blk - 4224) * 256 + threadIdx.x;  // 0..65535
    int q = i >> 7;
    int r = i & 127;
    float v;
    if (q < 128)
      v = Wa1[r * 128 + q];
    else if (q < 256)
      v = Wf1[r * 128 + (q - 128)] - Wf1[(128 + r) * 128 + (q - 128)];
    else {
      int c = (q - 256) >> 1;
      if (((q - 256) & 1) == 0)
        v = Wa1[(128 + r) * 128 + c];
      else
        v = Wf1[(128 + r) * 128 + c];
    }
    WT[i] = f2bf(v);
  }
}

// ---------------------------------------------------------------------------
// Kernel 2: exact kNN, wave per 4 queries (R9 structure, R9 unrolls).
// Pass A screens candidates 0..3071 with e2 for the 17th-smallest lane-min
// bound; pass B gathers e2 <= ub over all 4096; pass C recomputes
// reference-exact bits, excludes self, lex-sorts (adaptive 32/64-lane).
// ---------------------------------------------------------------------------
__global__ __launch_bounds__(256, 8) void k_knn(const float4* __restrict__ cc4,
                                                int* __restrict__ idx) {
  __shared__ unsigned cbuf[4][4][64];
  __shared__ unsigned scnt[4][4];
  int wave = threadIdx.x >> 6, lane = threadIdx.x & 63;
  int gw = blockIdx.x * 4 + wave;  // 0..8191
  int b = gw >> 10;
  int qbase = (gw & 1023) * 4;
  const float4* cb = cc4 + (size_t)b * K_;
  if (lane < 4) scnt[wave][lane] = 0u;
  __asm__ volatile("s_waitcnt lgkmcnt(0)" ::: "memory");
  float4 Q[4];
  float qx2[4], qy2[4], qz2[4];
#pragma unroll
  for (int qq = 0; qq < 4; ++qq) {
    Q[qq] = cb[qbase + qq];
    qx2[qq] = 2.0f * Q[qq].x;
    qy2[qq] = 2.0f * Q[qq].y;
    qz2[qq] = 2.0f * Q[qq].z;
  }

  // ---- pass A: per-lane min of e2 over 48-candidate slice (3072 total) ----
  float m0 = 1e30f, m1 = 1e30f, m2 = 1e30f, m3 = 1e30f;
#pragma unroll 4
  for (int it = 0; it < 48; ++it) {
    float4 c = cb[(it << 6) + lane];
    m0 = fminf(m0, escr2(qx2[0], qy2[0], qz2[0], c));
    m1 = fminf(m1, escr2(qx2[1], qy2[1], qz2[1], c));
    m2 = fminf(m2, escr2(qx2[2], qy2[2], qz2[2], c));
    m3 = fminf(m3, escr2(qx2[3], qy2[3], qz2[3], c));
  }
  // ---- bound = 17th smallest lane-min + slack (e2-space) ----
  float ub[4];
  float mv[4] = {m0, m1, m2, m3};
#pragma unroll
  for (int qq = 0; qq < 4; ++qq) {
    float v = mv[qq];
#pragma unroll
    for (int k = 2; k <= 64; k <<= 1) {
#pragma unroll
      for (int jj = k >> 1; jj >= 1; jj >>= 1) {
        float o = __shfl_xor(v, jj);
        bool amHigh = (lane & jj) != 0;
        bool up = (lane & k) != 0;
        bool gt = v > o;
        bool take = (amHigh ? !gt : gt) ^ up;
        v = take ? o : v;
      }
    }
    ub[qq] = __shfl(v, 16) + 1e-3f;
  }

  // ---- pass B: gather indices with e2 <= ub (self gathered, excl in C) ----
#pragma unroll 2
  for (int it = 0; it < 64; ++it) {
    int j = (it << 6) + lane;
    float4 c = cb[j];
#pragma unroll
    for (int qq = 0; qq < 4; ++qq) {
      float e = escr2(qx2[qq], qy2[qq], qz2[qq], c);
      if (e <= ub[qq]) {
        unsigned pos = atomicAdd(&scnt[wave][qq], 1u);
        if (pos < 64u) cbuf[wave][qq][pos] = (unsigned)j;
      }
    }
  }
  __asm__ volatile("s_waitcnt lgkmcnt(0)" ::: "memory");

  // ---- pass C: exact recompute, self-exclude, lex sort (adaptive) ----
#pragma unroll
  for (int qq = 0; qq < 4; ++qq) {
    unsigned m = scnt[wave][qq];
    m = m < 64u ? m : 64u;
    bool valid = lane < (int)m;
    unsigned ji = valid ? cbuf[wave][qq][lane] : 0u;
    if (valid && ji == (unsigned)(qbase + qq)) valid = false;
    float4 c = cb[ji];
    float dC = valid ? dist_exact(Q[qq], c) : 1e30f;
    int iC = valid ? (int)ji : 0x7fffffff;
#define SORT_STAGE(KV)                                              \
  {                                                                 \
    const int k = (KV);                                             \
    for (int jj = k >> 1; jj >= 1; jj >>= 1) {                      \
      float od = __shfl_xor(dC, jj);                                \
      int oi = __shfl_xor(iC, jj);                                  \
      bool amHigh = (lane & jj) != 0;                               \
      bool up = (lane & k) != 0;                                    \
      bool gt = (dC > od) || (dC == od && iC > oi);                 \
      bool take = (amHigh ? !gt : gt) ^ up;                         \
      dC = take ? od : dC;                                          \
      iC = take ? oi : iC;                                          \
    }                                                               \
  }
    if (m <= 32u) {
      SORT_STAGE(2) SORT_STAGE(4) SORT_STAGE(8) SORT_STAGE(16) SORT_STAGE(32)
    } else {
      SORT_STAGE(2) SORT_STAGE(4) SORT_STAGE(8) SORT_STAGE(16) SORT_STAGE(32)
      SORT_STAGE(64)
    }
#undef SORT_STAGE
    if (lane < KN)
      idx[((size_t)b * K_ + (qbase + qq)) * KN + lane] = iC;
  }
}

// ---------------------------------------------------------------------------
// Kernel 3: MFMA GEMM  SN_bf16[32768,512] = A_bf16[32768,128] @ WcatT^T
// 128x128 tile, 4 waves. batch = blockIdx&7 -> batch b L2-resident on XCD b.
// Epilogue repacks through LDS for coalesced dwordx4 stores.
// ---------------------------------------------------------------------------
__global__ __launch_bounds__(256) void k_gemm_mfma(
    const unsigned short* __restrict__ A, const unsigned short* __restrict__ BT,
    unsigned short* __restrict__ SN) {
  __shared__ char lB[32768];
  int bb = blockIdx.x & 7;
  int rest = blockIdx.x >> 3;
  int mbl = rest >> 2, nb = rest & 3;
  int m0 = bb * 4096 + mbl * 128, n0 = nb * 128;
  int t = threadIdx.x;
  {
    const char* src = (const char*)(BT + (size_t)n0 * 128);
#pragma unroll
    for (int i = 0; i < 8; ++i) {
      int byte = (t + i * 256) * 16;
      int n = byte >> 8;
      int sb = byte ^ ((n & 7) << 4);
      *(float4*)(lB + sb) = *(const float4*)(src + byte);
    }
  }
  __syncthreads();
  int wave = t >> 6, lane = t & 63;
  int wr = wave >> 1, wc = wave & 1;
  int lm = lane & 15, lk = lane >> 4;
  f32x4 z = {0.f, 0.f, 0.f, 0.f};
  f32x4 acc00 = z, acc01 = z, acc02 = z, acc03 = z;
  f32x4 acc10 = z, acc11 = z, acc12 = z, acc13 = z;
  f32x4 acc20 = z, acc21 = z, acc22 = z, acc23 = z;
  f32x4 acc30 = z, acc31 = z, acc32 = z, acc33 = z;
  const char* abase =
      (const char*)A + (size_t)(m0 + wr * 64 + lm) * 256 + lk * 16;
#pragma unroll
  for (int ks = 0; ks < 4; ++ks) {
    bf16x8 af[4], bfr[4];
#pragma unroll
    for (int mt = 0; mt < 4; ++mt)
      af[mt] = *(const bf16x8*)(abase + (size_t)mt * 4096 + ks * 64);
#pragma unroll
    for (int nt = 0; nt < 4; ++nt) {
      int n_local = wc * 64 + nt * 16 + lm;
      int byte = n_local * 256 + ks * 64 + lk * 16;
      byte ^= (n_local & 7) << 4;
      bfr[nt] = *(const bf16x8*)(lB + byte);
    }
    acc00 = __builtin_amdgcn_mfma_f32_16x16x32_bf16(af[0], bfr[0], acc00, 0, 0, 0);
    acc01 = __builtin_amdgcn_mfma_f32_16x16x32_bf16(af[0], bfr[1], acc01, 0, 0, 0);
    acc02 = __builtin_amdgcn_mfma_f32_16x16x32_bf16(af[0], bfr[2], acc02, 0, 0, 0);
    acc03 = __builtin_amdgcn_mfma_f32_16x16x32_bf16(af[0], bfr[3], acc03, 0, 0, 0);
    acc10 = __builtin_amdgcn_mfma_f32_16x16x32_bf16(af[1], bfr[0], acc10, 0, 0, 0);
    acc11 = __builtin_amdgcn_mfma_f32_16x16x32_bf16(af[1], bfr[1], acc11, 0, 0, 0);
    acc12 = __builtin_amdgcn_mfma_f32_16x16x32_bf16(af[1], bfr[2], acc12, 0, 0, 0);
    acc13 = __builtin_amdgcn_mfma_f32_16x16x32_bf16(af[1], bfr[3], acc13, 0, 0, 0);
    acc20 = __builtin_amdgcn_mfma_f32_16x16x32_bf16(af[2], bfr[0], acc20, 0, 0, 0);
    acc21 = __builtin_amdgcn_mfma_f32_16x16x32_bf16(af[2], bfr[1], acc21, 0, 0, 0);
    acc22 = __builtin_amdgcn_mfma_f32_16x16x32_bf16(af[2], bfr[2], acc22, 0, 0, 0);
    acc23 = __builtin_amdgcn_mfma_f32_16x16x32_bf16(af[2], bfr[3], acc23, 0, 0, 0);
    acc30 = __builtin_amdgcn_mfma_f32_16x16x32_bf16(af[3], bfr[0], acc30, 0, 0, 0);
    acc31 = __builtin_amdgcn_mfma_f32_16x16x32_bf16(af[3], bfr[1], acc31, 0, 0, 0);
    acc32 = __builtin_amdgcn_mfma_f32_16x16x32_bf16(af[3], bfr[2], acc32, 0, 0, 0);
    acc33 = __builtin_amdgcn_mfma_f32_16x16x32_bf16(af[3], bfr[3], acc33, 0, 0, 0);
  }
  f32x4 accs[4][4] = {{acc00, acc01, acc02, acc03},
                      {acc10, acc11, acc12, acc13},
                      {acc20, acc21, acc22, acc23},
                      {acc30, acc31, acc32, acc33}};
  // epilogue: accs -> LDS bf16 tile [128][128], then coalesced dwordx4 out
  __syncthreads();  // all waves done reading lB
  unsigned short* lC = (unsigned short*)lB;
#pragma unroll
  for (int mt = 0; mt < 4; ++mt) {
#pragma unroll
    for (int nt = 0; nt < 4; ++nt) {
#pragma unroll
      for (int r = 0; r < 4; ++r) {
        int row = wr * 64 + mt * 16 + lk * 4 + r;
        int col = wc * 64 + nt * 16 + lm;
        lC[row * 128 + col] = f2bf(accs[mt][nt][r]);
      }
    }
  }
  __syncthreads();
  {
    unsigned short* dst = SN + (size_t)m0 * 512 + n0;
#pragma unroll
    for (int i = 0; i < 8; ++i) {
      int e = (t + i * 256) * 8;  // element offset, 8 bf16 = 16B
      int row = e >> 7;
      int col = e & 127;
      *(f32x4*)(dst + (size_t)row * 512 + col) = *(const f32x4*)(lC + e);
    }
  }
}

// ---------------------------------------------------------------------------
// Kernel 4: attention aggregate. Wave per point; lane (g=lane>>4, r=lane&15)
// handles channels [8r,8r+8) of neighbors {g,4+g,8+g,12+g}.
// ---------------------------------------------------------------------------
__global__ __launch_bounds__(256) void k_attn(
    const unsigned short* __restrict__ SN, const int* __restrict__ idx,
    const float* __restrict__ b_a1, const float* __restrict__ b_f1,
    const float* __restrict__ W_a2, const float* __restrict__ b_a2,
    float* __restrict__ out) {
  int wave = threadIdx.x >> 6, lane = threadIdx.x & 63;
  int g = lane >> 4, r = lane & 15;
  int b = blockIdx.x & 7;
  int w = blockIdx.x >> 3;  // 0..1023
  size_t gpt = (size_t)b * K_ + w * 4 + wave;
  const unsigned short* sr = SN + gpt * 512;
  bf16x8 sa8 = *(const bf16x8*)(sr + 8 * r);
  bf16x8 sf8 = *(const bf16x8*)(sr + 128 + 8 * r);
  float4 bav0 = *(const float4*)(b_a1 + 8 * r);
  float4 bav1 = *(const float4*)(b_a1 + 8 * r + 4);
  float4 bfv0 = *(const float4*)(b_f1 + 8 * r);
  float4 bfv1 = *(const float4*)(b_f1 + 8 * r + 4);
  float4 w2v0 = *(const float4*)(W_a2 + 8 * r);
  float4 w2v1 = *(const float4*)(W_a2 + 8 * r + 4);
  float sab[8], sfb[8], w2v[8];
  {
    float bav[8] = {bav0.x, bav0.y, bav0.z, bav0.w, bav1.x, bav1.y, bav1.z, bav1.w};
    float bfv[8] = {bfv0.x, bfv0.y, bfv0.z, bfv0.w, bfv1.x, bfv1.y, bfv1.z, bfv1.w};
    float wv[8] = {w2v0.x, w2v0.y, w2v0.z, w2v0.w, w2v1.x, w2v1.y, w2v1.z, w2v1.w};
#pragma unroll
    for (int i = 0; i < 8; ++i) {
      sab[i] = bf2f((unsigned short)sa8[i]) + bav[i];
      sfb[i] = bf2f((unsigned short)sf8[i]) + bfv[i];
      w2v[i] = wv[i];
    }
  }
  float ba2v = b_a2[0];
  int nv = 0;
  if (lane < 16) nv = idx[gpt * 16 + lane];
  float lgl[4];
  float tsv[4][8];
#pragma unroll
  for (int round = 0; round < 4; ++round) {
    int n = __shfl(nv, round * 4 + g);
    const unsigned short* nr =
        SN + ((size_t)b * K_ + n) * 512 + 256 + 16 * r;
    bf16x8 u0 = *(const bf16x8*)(nr);
    bf16x8 u1 = *(const bf16x8*)(nr + 8);
    float dot = 0.0f;
#pragma unroll
    for (int i = 0; i < 4; ++i) {
      float h = sab[i] + bf2f((unsigned short)u0[2 * i]);
      h = h >= 0.0f ? h : 0.2f * h;
      float tv = sfb[i] + bf2f((unsigned short)u0[2 * i + 1]);
      tv = tv >= 0.0f ? tv : 0.2f * tv;
      dot = fmaf(h, w2v[i], dot);
      tsv[round][i] = tv;
    }
#pragma unroll
    for (int i = 0; i < 4; ++i) {
      float h = sab[4 + i] + bf2f((unsigned short)u1[2 * i]);
      h = h >= 0.0f ? h : 0.2f * h;
      float tv = sfb[4 + i] + bf2f((unsigned short)u1[2 * i + 1]);
      tv = tv >= 0.0f ? tv : 0.2f * tv;
      dot = fmaf(h, w2v[4 + i], dot);
      tsv[round][4 + i] = tv;
    }
#pragma unroll
    for (int o = 1; o < 16; o <<= 1) dot += __shfl_xor(dot, o);
    lgl[round] = dot + ba2v;
  }
  float mx = fmaxf(fmaxf(lgl[0], lgl[1]), fmaxf(lgl[2], lgl[3]));
  mx = fmaxf(mx, __shfl_xor(mx, 16));
  mx = fmaxf(mx, __shfl_xor(mx, 32));
  float e[4];
  float s = 0.0f;
#pragma unroll
  for (int round = 0; round < 4; ++round) {
    e[round] = expf(lgl[round] - mx);
    s += e[round];
  }
  s += __shfl_xor(s, 16);
  s += __shfl_xor(s, 32);
  float inv = 1.0f / s;
  float o8[8] = {0, 0, 0, 0, 0, 0, 0, 0};
#pragma unroll
  for (int round = 0; round < 4; ++round) {
    float a = e[round] * inv;
#pragma unroll
    for (int i = 0; i < 8; ++i) o8[i] = fmaf(a, tsv[round][i], o8[i]);
  }
#pragma unroll
  for (int i = 0; i < 8; ++i) {
    o8[i] += __shfl_xor(o8[i], 16);
    o8[i] += __shfl_xor(o8[i], 32);
  }
  if (g == 0) {
    float* op = out + gpt * 128 + 8 * r;
    *(float4*)op = make_float4(o8[0], o8[1], o8[2], o8[3]);
    *(float4*)(op + 4) = make_float4(o8[4], o8[5], o8[6], o8[7]);
  }
}

// ---------------------------------------------------------------------------
extern "C" void kernel_launch(void* const* d_in, const int* in_sizes, int n_in,
                              void* d_out, int out_size, void* d_ws,
                              size_t ws_size, hipStream_t stream) {
  const float* x = (const float*)d_in[0];
  const float* pos = (const float*)d_in[1];
  const float* coords = (const float*)d_in[2];
  const float* gamma = (const float*)d_in[3];
  const float* beta = (const float*)d_in[4];
  const float* Wa1 = (const float*)d_in[5];
  const float* ba1 = (const float*)d_in[6];
  const float* Wa2 = (const float*)d_in[7];
  const float* ba2 = (const float*)d_in[8];
  const float* Wf1 = (const float*)d_in[9];
  const float* bf1 = (const float*)d_in[10];
  float* out = (float*)d_out;

  char* ws = (char*)d_ws;
  unsigned short* A = (unsigned short*)ws;                                // 8MB
  unsigned short* SN = (unsigned short*)(ws + (size_t)16 * 1024 * 1024);  // 32MB
  unsigned short* WT = (unsigned short*)(ws + (size_t)80 * 1024 * 1024);  // 128KB
  int* idx = (int*)(ws + (size_t)80 * 1024 * 1024 + 512 * 1024);          // 2MB
  float4* cc4 = (float4*)(ws + (size_t)80 * 1024 * 1024 + 2560 * 1024);   // 512KB

  k_pre<<<4480, 256, 0, stream>>>(x, pos, gamma, beta, Wa1, Wf1, coords, A, WT,
                                  cc4);
  k_knn<<<2048, 256, 0, stream>>>(cc4, idx);
  k_gemm_mfma<<<1024, 256, 0, stream>>>(A, WT, SN);
  k_attn<<<8192, 256, 0, stream>>>(SN, idx, ba1, bf1, Wa2, ba2, out);
}

// Round 15
// 106.404 us; speedup vs baseline: 2.9526x; 1.0453x over previous
//
#include <hip/hip_runtime.h>

#define B_ 8
#define K_ 4096
#define C_ 128
#define KN 16

typedef __attribute__((ext_vector_type(8))) short bf16x8;
typedef __attribute__((ext_vector_type(4))) float f32x4;

struct f3 {
  float x, y, z;
};

__device__ __forceinline__ unsigned short f2bf(float f) {
  unsigned u = __float_as_uint(f);
  unsigned r = (u + 0x7FFFu + ((u >> 16) & 1u)) >> 16;
  return (unsigned short)r;
}
__device__ __forceinline__ float bf2f(unsigned short s) {
  return __uint_as_float(((unsigned)s) << 16);
}

// ---------------------------------------------------------------------------
// Kernel 1 (fused pre): lnpos (float4, 2 rows/wave) | wcatT
// WT col layout: [0:128]=S_a, [128:256]=S_f, [256:512] interleaved
// (256+2c = N_a[c], 257+2c = N_f[c]).
// ---------------------------------------------------------------------------
__global__ __launch_bounds__(256) void k_pre(
    const float* __restrict__ x, const float* __restrict__ pos,
    const float* __restrict__ gamma, const float* __restrict__ beta,
    const float* __restrict__ Wa1, const float* __restrict__ Wf1,
    unsigned short* __restrict__ A, unsigned short* __restrict__ WT) {
  int blk = blockIdx.x;
  if (blk < 4096) {
    // LayerNorm + pos: wave handles 2 rows; lane l -> row (l>>5), chans 4*(l&31)
    int wave = threadIdx.x >> 6;
    int lane = threadIdx.x & 63;
    int l32 = lane & 31;
    size_t row = (size_t)blk * 8 + wave * 2 + (lane >> 5);
    float4 a = ((const float4*)(x + row * C_))[l32];
    float s = (a.x + a.y) + (a.z + a.w);
#pragma unroll
    for (int o = 1; o < 32; o <<= 1) s += __shfl_xor(s, o);
    float mu = s * (1.0f / 128.0f);
    float d0 = a.x - mu, d1 = a.y - mu, d2 = a.z - mu, d3 = a.w - mu;
    float v = (d0 * d0 + d1 * d1) + (d2 * d2 + d3 * d3);
#pragma unroll
    for (int o = 1; o < 32; o <<= 1) v += __shfl_xor(v, o);
    float rstd = rsqrtf(v * (1.0f / 128.0f) + 1e-5f);
    float4 gm = ((const float4*)gamma)[l32];
    float4 bt = ((const float4*)beta)[l32];
    float4 pp = ((const float4*)(pos + row * C_))[l32];
    float o0 = d0 * rstd * gm.x + bt.x + pp.x;
    float o1 = d1 * rstd * gm.y + bt.y + pp.y;
    float o2 = d2 * rstd * gm.z + bt.z + pp.z;
    float o3 = d3 * rstd * gm.w + bt.w + pp.w;
    ushort4 o = make_ushort4(f2bf(o0), f2bf(o1), f2bf(o2), f2bf(o3));
    *(ushort4*)(A + row * C_ + 4 * l32) = o;
  } else {
    int i = (blk - 4096) * 256 + threadIdx.x;  // 0..65535
    int q = i >> 7;
    int r = i & 127;
    float v;
    if (q < 128)
      v = Wa1[r * 128 + q];
    else if (q < 256)
      v = Wf1[r * 128 + (q - 128)] - Wf1[(128 + r) * 128 + (q - 128)];
    else {
      int c = (q - 256) >> 1;
      if (((q - 256) & 1) == 0)
        v = Wa1[(128 + r) * 128 + c];
      else
        v = Wf1[(128 + r) * 128 + c];
    }
    WT[i] = f2bf(v);
  }
}

// ---------------------------------------------------------------------------
// Kernel 2: exact kNN, wave per 4 queries, raw float3 candidate reads
// (12B/candidate). Pass A screens candidates 0..3071 with the fast screen
// e2 = wf - 2 q.c (wf computed in-loop, shared by 4 queries) for the
// 17th-smallest lane-min bound; pass B gathers e2 <= ub over all 4096;
// pass C recomputes reference-exact distance bits for the gathered <=64,
// excludes self, lex-sorts (adaptive 32/64). Selected set == reference.
// ---------------------------------------------------------------------------
__global__ __launch_bounds__(256, 8) void k_knn(const float* __restrict__ coords,
                                                int* __restrict__ idx) {
  __shared__ unsigned cbuf[4][4][64];
  __shared__ unsigned scnt[4][4];
  int wave = threadIdx.x >> 6, lane = threadIdx.x & 63;
  int gw = blockIdx.x * 4 + wave;  // 0..8191
  int b = gw >> 10;
  int qbase = (gw & 1023) * 4;
  const float* cb = coords + (size_t)b * K_ * 3;
  if (lane < 4) scnt[wave][lane] = 0u;
  __asm__ volatile("s_waitcnt lgkmcnt(0)" ::: "memory");
  float qx[4], qy[4], qz[4], qwE[4], qx2[4], qy2[4], qz2[4];
#pragma unroll
  for (int qq = 0; qq < 4; ++qq) {
    f3 q = *(const f3*)(cb + (size_t)(qbase + qq) * 3);
    qx[qq] = q.x;
    qy[qq] = q.y;
    qz[qq] = q.z;
    // exact xx bits (reference association)
    qwE[qq] = __fadd_rn(__fadd_rn(__fmul_rn(q.x, q.x), __fmul_rn(q.y, q.y)),
                        __fmul_rn(q.z, q.z));
    qx2[qq] = 2.0f * q.x;
    qy2[qq] = 2.0f * q.y;
    qz2[qq] = 2.0f * q.z;
  }

  // ---- pass A: per-lane min of e2 over 48-candidate slice (3072 total) ----
  float m0 = 1e30f, m1 = 1e30f, m2 = 1e30f, m3 = 1e30f;
#pragma unroll 4
  for (int it = 0; it < 48; ++it) {
    int j = (it << 6) + lane;
    f3 c = *(const f3*)(cb + (size_t)j * 3);
    float wf = fmaf(c.x, c.x, fmaf(c.y, c.y, c.z * c.z));
    m0 = fminf(m0, fmaf(-qx2[0], c.x, fmaf(-qy2[0], c.y, fmaf(-qz2[0], c.z, wf))));
    m1 = fminf(m1, fmaf(-qx2[1], c.x, fmaf(-qy2[1], c.y, fmaf(-qz2[1], c.z, wf))));
    m2 = fminf(m2, fmaf(-qx2[2], c.x, fmaf(-qy2[2], c.y, fmaf(-qz2[2], c.z, wf))));
    m3 = fminf(m3, fmaf(-qx2[3], c.x, fmaf(-qy2[3], c.y, fmaf(-qz2[3], c.z, wf))));
  }
  // ---- bound = 17th smallest lane-min + slack (e2-space) ----
  float ub[4];
  float mv[4] = {m0, m1, m2, m3};
#pragma unroll
  for (int qq = 0; qq < 4; ++qq) {
    float v = mv[qq];
#pragma unroll
    for (int k = 2; k <= 64; k <<= 1) {
#pragma unroll
      for (int jj = k >> 1; jj >= 1; jj >>= 1) {
        float o = __shfl_xor(v, jj);
        bool amHigh = (lane & jj) != 0;
        bool up = (lane & k) != 0;
        bool gt = v > o;
        bool take = (amHigh ? !gt : gt) ^ up;
        v = take ? o : v;
      }
    }
    ub[qq] = __shfl(v, 16) + 1e-3f;
  }

  // ---- pass B: gather indices with e2 <= ub (self gathered, excl in C) ----
#pragma unroll 2
  for (int it = 0; it < 64; ++it) {
    int j = (it << 6) + lane;
    f3 c = *(const f3*)(cb + (size_t)j * 3);
    float wf = fmaf(c.x, c.x, fmaf(c.y, c.y, c.z * c.z));
#pragma unroll
    for (int qq = 0; qq < 4; ++qq) {
      float e = fmaf(-qx2[qq], c.x,
                     fmaf(-qy2[qq], c.y, fmaf(-qz2[qq], c.z, wf)));
      if (e <= ub[qq]) {
        unsigned pos = atomicAdd(&scnt[wave][qq], 1u);
        if (pos < 64u) cbuf[wave][qq][pos] = (unsigned)j;
      }
    }
  }
  __asm__ volatile("s_waitcnt lgkmcnt(0)" ::: "memory");

  // ---- pass C: exact recompute, self-exclude, lex sort (adaptive) ----
#pragma unroll
  for (int qq = 0; qq < 4; ++qq) {
    unsigned m = scnt[wave][qq];
    m = m < 64u ? m : 64u;
    bool valid = lane < (int)m;
    unsigned ji = valid ? cbuf[wave][qq][lane] : 0u;
    if (valid && ji == (unsigned)(qbase + qq)) valid = false;
    f3 c = *(const f3*)(cb + (size_t)ji * 3);
    float dC = 1e30f;
    int iC = 0x7fffffff;
    if (valid) {
      float cw = __fadd_rn(__fadd_rn(__fmul_rn(c.x, c.x), __fmul_rn(c.y, c.y)),
                           __fmul_rn(c.z, c.z));
      float dot = __fadd_rn(
          __fadd_rn(__fmul_rn(qx[qq], c.x), __fmul_rn(qy[qq], c.y)),
          __fmul_rn(qz[qq], c.z));
      dC = __fadd_rn(__fadd_rn(qwE[qq], cw), __fmul_rn(-2.0f, dot));
      iC = (int)ji;
    }
#define SORT_STAGE(KV)                                              \
  {                                                                 \
    const int k = (KV);                                             \
    for (int jj = k >> 1; jj >= 1; jj >>= 1) {                      \
      float od = __shfl_xor(dC, jj);                                \
      int oi = __shfl_xor(iC, jj);                                  \
      bool amHigh = (lane & jj) != 0;                               \
      bool up = (lane & k) != 0;                                    \
      bool gt = (dC > od) || (dC == od && iC > oi);                 \
      bool take = (amHigh ? !gt : gt) ^ up;                         \
      dC = take ? od : dC;                                          \
      iC = take ? oi : iC;                                          \
    }                                                               \
  }
    if (m <= 32u) {
      SORT_STAGE(2) SORT_STAGE(4) SORT_STAGE(8) SORT_STAGE(16) SORT_STAGE(32)
    } else {
      SORT_STAGE(2) SORT_STAGE(4) SORT_STAGE(8) SORT_STAGE(16) SORT_STAGE(32)
      SORT_STAGE(64)
    }
#undef SORT_STAGE
    if (lane < KN)
      idx[((size_t)b * K_ + (qbase + qq)) * KN + lane] = iC;
  }
}

// ---------------------------------------------------------------------------
// Kernel 3: MFMA GEMM  SN_bf16[32768,512] = A_bf16[32768,128] @ WcatT^T
// 128x128 tile, 4 waves. batch = blockIdx&7 -> batch b L2-resident on XCD b.
// Epilogue repacks through LDS for coalesced dwordx4 stores.
// ---------------------------------------------------------------------------
__global__ __launch_bounds__(256) void k_gemm_mfma(
    const unsigned short* __restrict__ A, const unsigned short* __restrict__ BT,
    unsigned short* __restrict__ SN) {
  __shared__ char lB[32768];
  int bb = blockIdx.x & 7;
  int rest = blockIdx.x >> 3;
  int mbl = rest >> 2, nb = rest & 3;
  int m0 = bb * 4096 + mbl * 128, n0 = nb * 128;
  int t = threadIdx.x;
  {
    const char* src = (const char*)(BT + (size_t)n0 * 128);
#pragma unroll
    for (int i = 0; i < 8; ++i) {
      int byte = (t + i * 256) * 16;
      int n = byte >> 8;
      int sb = byte ^ ((n & 7) << 4);
      *(float4*)(lB + sb) = *(const float4*)(src + byte);
    }
  }
  __syncthreads();
  int wave = t >> 6, lane = t & 63;
  int wr = wave >> 1, wc = wave & 1;
  int lm = lane & 15, lk = lane >> 4;
  f32x4 z = {0.f, 0.f, 0.f, 0.f};
  f32x4 acc00 = z, acc01 = z, acc02 = z, acc03 = z;
  f32x4 acc10 = z, acc11 = z, acc12 = z, acc13 = z;
  f32x4 acc20 = z, acc21 = z, acc22 = z, acc23 = z;
  f32x4 acc30 = z, acc31 = z, acc32 = z, acc33 = z;
  const char* abase =
      (const char*)A + (size_t)(m0 + wr * 64 + lm) * 256 + lk * 16;
#pragma unroll
  for (int ks = 0; ks < 4; ++ks) {
    bf16x8 af[4], bfr[4];
#pragma unroll
    for (int mt = 0; mt < 4; ++mt)
      af[mt] = *(const bf16x8*)(abase + (size_t)mt * 4096 + ks * 64);
#pragma unroll
    for (int nt = 0; nt < 4; ++nt) {
      int n_local = wc * 64 + nt * 16 + lm;
      int byte = n_local * 256 + ks * 64 + lk * 16;
      byte ^= (n_local & 7) << 4;
      bfr[nt] = *(const bf16x8*)(lB + byte);
    }
    acc00 = __builtin_amdgcn_mfma_f32_16x16x32_bf16(af[0], bfr[0], acc00, 0, 0, 0);
    acc01 = __builtin_amdgcn_mfma_f32_16x16x32_bf16(af[0], bfr[1], acc01, 0, 0, 0);
    acc02 = __builtin_amdgcn_mfma_f32_16x16x32_bf16(af[0], bfr[2], acc02, 0, 0, 0);
    acc03 = __builtin_amdgcn_mfma_f32_16x16x32_bf16(af[0], bfr[3], acc03, 0, 0, 0);
    acc10 = __builtin_amdgcn_mfma_f32_16x16x32_bf16(af[1], bfr[0], acc10, 0, 0, 0);
    acc11 = __builtin_amdgcn_mfma_f32_16x16x32_bf16(af[1], bfr[1], acc11, 0, 0, 0);
    acc12 = __builtin_amdgcn_mfma_f32_16x16x32_bf16(af[1], bfr[2], acc12, 0, 0, 0);
    acc13 = __builtin_amdgcn_mfma_f32_16x16x32_bf16(af[1], bfr[3], acc13, 0, 0, 0);
    acc20 = __builtin_amdgcn_mfma_f32_16x16x32_bf16(af[2], bfr[0], acc20, 0, 0, 0);
    acc21 = __builtin_amdgcn_mfma_f32_16x16x32_bf16(af[2], bfr[1], acc21, 0, 0, 0);
    acc22 = __builtin_amdgcn_mfma_f32_16x16x32_bf16(af[2], bfr[2], acc22, 0, 0, 0);
    acc23 = __builtin_amdgcn_mfma_f32_16x16x32_bf16(af[2], bfr[3], acc23, 0, 0, 0);
    acc30 = __builtin_amdgcn_mfma_f32_16x16x32_bf16(af[3], bfr[0], acc30, 0, 0, 0);
    acc31 = __builtin_amdgcn_mfma_f32_16x16x32_bf16(af[3], bfr[1], acc31, 0, 0, 0);
    acc32 = __builtin_amdgcn_mfma_f32_16x16x32_bf16(af[3], bfr[2], acc32, 0, 0, 0);
    acc33 = __builtin_amdgcn_mfma_f32_16x16x32_bf16(af[3], bfr[3], acc33, 0, 0, 0);
  }
  f32x4 accs[4][4] = {{acc00, acc01, acc02, acc03},
                      {acc10, acc11, acc12, acc13},
                      {acc20, acc21, acc22, acc23},
                      {acc30, acc31, acc32, acc33}};
  // epilogue: accs -> LDS bf16 tile [128][128], then coalesced dwordx4 out
  __syncthreads();  // all waves done reading lB
  unsigned short* lC = (unsigned short*)lB;
#pragma unroll
  for (int mt = 0; mt < 4; ++mt) {
#pragma unroll
    for (int nt = 0; nt < 4; ++nt) {
#pragma unroll
      for (int r = 0; r < 4; ++r) {
        int row = wr * 64 + mt * 16 + lk * 4 + r;
        int col = wc * 64 + nt * 16 + lm;
        lC[row * 128 + col] = f2bf(accs[mt][nt][r]);
      }
    }
  }
  __syncthreads();
  {
    unsigned short* dst = SN + (size_t)m0 * 512 + n0;
#pragma unroll
    for (int i = 0; i < 8; ++i) {
      int e = (t + i * 256) * 8;  // element offset, 8 bf16 = 16B
      int row = e >> 7;
      int col = e & 127;
      *(f32x4*)(dst + (size_t)row * 512 + col) = *(const f32x4*)(lC + e);
    }
  }
}

// ---------------------------------------------------------------------------
// Kernel 4: attention aggregate. Wave per point; lane (g=lane>>4, r=lane&15)
// handles channels [8r,8r+8) of neighbors {g,4+g,8+g,12+g}.
// ---------------------------------------------------------------------------
__global__ __launch_bounds__(256) void k_attn(
    const unsigned short* __restrict__ SN, const int* __restrict__ idx,
    const float* __restrict__ b_a1, const float* __restrict__ b_f1,
    const float* __restrict__ W_a2, const float* __restrict__ b_a2,
    float* __restrict__ out) {
  int wave = threadIdx.x >> 6, lane = threadIdx.x & 63;
  int g = lane >> 4, r = lane & 15;
  int b = blockIdx.x & 7;
  int w = blockIdx.x >> 3;  // 0..1023
  size_t gpt = (size_t)b * K_ + w * 4 + wave;
  const unsigned short* sr = SN + gpt * 512;
  bf16x8 sa8 = *(const bf16x8*)(sr + 8 * r);
  bf16x8 sf8 = *(const bf16x8*)(sr + 128 + 8 * r);
  float4 bav0 = *(const float4*)(b_a1 + 8 * r);
  float4 bav1 = *(const float4*)(b_a1 + 8 * r + 4);
  float4 bfv0 = *(const float4*)(b_f1 + 8 * r);
  float4 bfv1 = *(const float4*)(b_f1 + 8 * r + 4);
  float4 w2v0 = *(const float4*)(W_a2 + 8 * r);
  float4 w2v1 = *(const float4*)(W_a2 + 8 * r + 4);
  float sab[8], sfb[8], w2v[8];
  {
    float bav[8] = {bav0.x, bav0.y, bav0.z, bav0.w, bav1.x, bav1.y, bav1.z, bav1.w};
    float bfv[8] = {bfv0.x, bfv0.y, bfv0.z, bfv0.w, bfv1.x, bfv1.y, bfv1.z, bfv1.w};
    float wv[8] = {w2v0.x, w2v0.y, w2v0.z, w2v0.w, w2v1.x, w2v1.y, w2v1.z, w2v1.w};
#pragma unroll
    for (int i = 0; i < 8; ++i) {
      sab[i] = bf2f((unsigned short)sa8[i]) + bav[i];
      sfb[i] = bf2f((unsigned short)sf8[i]) + bfv[i];
      w2v[i] = wv[i];
    }
  }
  float ba2v = b_a2[0];
  int nv = 0;
  if (lane < 16) nv = idx[gpt * 16 + lane];
  float lgl[4];
  float tsv[4][8];
#pragma unroll
  for (int round = 0; round < 4; ++round) {
    int n = __shfl(nv, round * 4 + g);
    const unsigned short* nr =
        SN + ((size_t)b * K_ + n) * 512 + 256 + 16 * r;
    bf16x8 u0 = *(const bf16x8*)(nr);
    bf16x8 u1 = *(const bf16x8*)(nr + 8);
    float dot = 0.0f;
#pragma unroll
    for (int i = 0; i < 4; ++i) {
      float h = sab[i] + bf2f((unsigned short)u0[2 * i]);
      h = h >= 0.0f ? h : 0.2f * h;
      float tv = sfb[i] + bf2f((unsigned short)u0[2 * i + 1]);
      tv = tv >= 0.0f ? tv : 0.2f * tv;
      dot = fmaf(h, w2v[i], dot);
      tsv[round][i] = tv;
    }
#pragma unroll
    for (int i = 0; i < 4; ++i) {
      float h = sab[4 + i] + bf2f((unsigned short)u1[2 * i]);
      h = h >= 0.0f ? h : 0.2f * h;
      float tv = sfb[4 + i] + bf2f((unsigned short)u1[2 * i + 1]);
      tv = tv >= 0.0f ? tv : 0.2f * tv;
      dot = fmaf(h, w2v[4 + i], dot);
      tsv[round][4 + i] = tv;
    }
#pragma unroll
    for (int o = 1; o < 16; o <<= 1) dot += __shfl_xor(dot, o);
    lgl[round] = dot + ba2v;
  }
  float mx = fmaxf(fmaxf(lgl[0], lgl[1]), fmaxf(lgl[2], lgl[3]));
  mx = fmaxf(mx, __shfl_xor(mx, 16));
  mx = fmaxf(mx, __shfl_xor(mx, 32));
  float e[4];
  float s = 0.0f;
#pragma unroll
  for (int round = 0; round < 4; ++round) {
    e[round] = expf(lgl[round] - mx);
    s += e[round];
  }
  s += __shfl_xor(s, 16);
  s += __shfl_xor(s, 32);
  float inv = 1.0f / s;
  float o8[8] = {0, 0, 0, 0, 0, 0, 0, 0};
#pragma unroll
  for (int round = 0; round < 4; ++round) {
    float a = e[round] * inv;
#pragma unroll
    for (int i = 0; i < 8; ++i) o8[i] = fmaf(a, tsv[round][i], o8[i]);
  }
#pragma unroll
  for (int i = 0; i < 8; ++i) {
    o8[i] += __shfl_xor(o8[i], 16);
    o8[i] += __shfl_xor(o8[i], 32);
  }
  if (g == 0) {
    float* op = out + gpt * 128 + 8 * r;
    *(float4*)op = make_float4(o8[0], o8[1], o8[2], o8[3]);
    *(float4*)(op + 4) = make_float4(o8[4], o8[5], o8[6], o8[7]);
  }
}

// ---------------------------------------------------------------------------
extern "C" void kernel_launch(void* const* d_in, const int* in_sizes, int n_in,
                              void* d_out, int out_size, void* d_ws,
                              size_t ws_size, hipStream_t stream) {
  const float* x = (const float*)d_in[0];
  const float* pos = (const float*)d_in[1];
  const float* coords = (const float*)d_in[2];
  const float* gamma = (const float*)d_in[3];
  const float* beta = (const float*)d_in[4];
  const float* Wa1 = (const float*)d_in[5];
  const float* ba1 = (const float*)d_in[6];
  const float* Wa2 = (const float*)d_in[7];
  const float* ba2 = (const float*)d_in[8];
  const float* Wf1 = (const float*)d_in[9];
  const float* bf1 = (const float*)d_in[10];
  float* out = (float*)d_out;

  char* ws = (char*)d_ws;
  unsigned short* A = (unsigned short*)ws;                                // 8MB
  unsigned short* SN = (unsigned short*)(ws + (size_t)16 * 1024 * 1024);  // 32MB
  unsigned short* WT = (unsigned short*)(ws + (size_t)80 * 1024 * 1024);  // 128KB
  int* idx = (int*)(ws + (size_t)80 * 1024 * 1024 + 512 * 1024);          // 2MB

  k_pre<<<4352, 256, 0, stream>>>(x, pos, gamma, beta, Wa1, Wf1, A, WT);
  k_knn<<<2048, 256, 0, stream>>>(coords, idx);
  k_gemm_mfma<<<1024, 256, 0, stream>>>(A, WT, SN);
  k_attn<<<8192, 256, 0, stream>>>(SN, idx, ba1, bf1, Wa2, ba2, out);
}

// Round 16
// 101.825 us; speedup vs baseline: 3.0853x; 1.0450x over previous
//
#include <hip/hip_runtime.h>

#define B_ 8
#define K_ 4096
#define C_ 128
#define KN 16

typedef __attribute__((ext_vector_type(8))) short bf16x8;
typedef __attribute__((ext_vector_type(4))) float f32x4;

struct f3 {
  float x, y, z;
};

__device__ __forceinline__ unsigned short f2bf(float f) {
  unsigned u = __float_as_uint(f);
  unsigned r = (u + 0x7FFFu + ((u >> 16) & 1u)) >> 16;
  return (unsigned short)r;
}
__device__ __forceinline__ float bf2f(unsigned short s) {
  return __uint_as_float(((unsigned)s) << 16);
}

// ---------------------------------------------------------------------------
// Kernel 1 (fused): blocks 0..2047 = exact kNN (R15 body verbatim);
// blocks 2048..6143 = lnpos; blocks 6144..6399 = wcatT.
// kNN blocks fill the machine first (8 blocks/CU); pre work tail-fills as
// kNN blocks retire. Saves one launch boundary; no co-resident interference.
// ---------------------------------------------------------------------------
__global__ __launch_bounds__(256, 8) void k_knnpre(
    const float* __restrict__ coords, int* __restrict__ idx,
    const float* __restrict__ x, const float* __restrict__ pos,
    const float* __restrict__ gamma, const float* __restrict__ beta,
    const float* __restrict__ Wa1, const float* __restrict__ Wf1,
    unsigned short* __restrict__ A, unsigned short* __restrict__ WT) {
  __shared__ unsigned cbuf[4][4][64];
  __shared__ unsigned scnt[4][4];
  int blk = blockIdx.x;
  if (blk >= 2048) {
    int blk2 = blk - 2048;
    if (blk2 < 4096) {
      // LayerNorm + pos: wave = 2 rows; lane l -> row (l>>5), chans 4*(l&31)
      int wave = threadIdx.x >> 6;
      int lane = threadIdx.x & 63;
      int l32 = lane & 31;
      size_t row = (size_t)blk2 * 8 + wave * 2 + (lane >> 5);
      float4 a = ((const float4*)(x + row * C_))[l32];
      float s = (a.x + a.y) + (a.z + a.w);
#pragma unroll
      for (int o = 1; o < 32; o <<= 1) s += __shfl_xor(s, o);
      float mu = s * (1.0f / 128.0f);
      float d0 = a.x - mu, d1 = a.y - mu, d2 = a.z - mu, d3 = a.w - mu;
      float v = (d0 * d0 + d1 * d1) + (d2 * d2 + d3 * d3);
#pragma unroll
      for (int o = 1; o < 32; o <<= 1) v += __shfl_xor(v, o);
      float rstd = rsqrtf(v * (1.0f / 128.0f) + 1e-5f);
      float4 gm = ((const float4*)gamma)[l32];
      float4 bt = ((const float4*)beta)[l32];
      float4 pp = ((const float4*)(pos + row * C_))[l32];
      float o0 = d0 * rstd * gm.x + bt.x + pp.x;
      float o1 = d1 * rstd * gm.y + bt.y + pp.y;
      float o2 = d2 * rstd * gm.z + bt.z + pp.z;
      float o3 = d3 * rstd * gm.w + bt.w + pp.w;
      ushort4 o = make_ushort4(f2bf(o0), f2bf(o1), f2bf(o2), f2bf(o3));
      *(ushort4*)(A + row * C_ + 4 * l32) = o;
    } else {
      int i = (blk2 - 4096) * 256 + threadIdx.x;  // 0..65535
      int q = i >> 7;
      int r = i & 127;
      float v;
      if (q < 128)
        v = Wa1[r * 128 + q];
      else if (q < 256)
        v = Wf1[r * 128 + (q - 128)] - Wf1[(128 + r) * 128 + (q - 128)];
      else {
        int c = (q - 256) >> 1;
        if (((q - 256) & 1) == 0)
          v = Wa1[(128 + r) * 128 + c];
        else
          v = Wf1[(128 + r) * 128 + c];
      }
      WT[i] = f2bf(v);
    }
    return;
  }

  // ======================= exact kNN (R15 body) =======================
  int wave = threadIdx.x >> 6, lane = threadIdx.x & 63;
  int gw = blk * 4 + wave;  // 0..8191
  int b = gw >> 10;
  int qbase = (gw & 1023) * 4;
  const float* cb = coords + (size_t)b * K_ * 3;
  if (lane < 4) scnt[wave][lane] = 0u;
  __asm__ volatile("s_waitcnt lgkmcnt(0)" ::: "memory");
  float qx[4], qy[4], qz[4], qwE[4], qx2[4], qy2[4], qz2[4];
#pragma unroll
  for (int qq = 0; qq < 4; ++qq) {
    f3 q = *(const f3*)(cb + (size_t)(qbase + qq) * 3);
    qx[qq] = q.x;
    qy[qq] = q.y;
    qz[qq] = q.z;
    qwE[qq] = __fadd_rn(__fadd_rn(__fmul_rn(q.x, q.x), __fmul_rn(q.y, q.y)),
                        __fmul_rn(q.z, q.z));
    qx2[qq] = 2.0f * q.x;
    qy2[qq] = 2.0f * q.y;
    qz2[qq] = 2.0f * q.z;
  }

  // pass A: per-lane min of e2 over 48-candidate slice (3072 total)
  float m0 = 1e30f, m1 = 1e30f, m2 = 1e30f, m3 = 1e30f;
#pragma unroll 4
  for (int it = 0; it < 48; ++it) {
    int j = (it << 6) + lane;
    f3 c = *(const f3*)(cb + (size_t)j * 3);
    float wf = fmaf(c.x, c.x, fmaf(c.y, c.y, c.z * c.z));
    m0 = fminf(m0, fmaf(-qx2[0], c.x, fmaf(-qy2[0], c.y, fmaf(-qz2[0], c.z, wf))));
    m1 = fminf(m1, fmaf(-qx2[1], c.x, fmaf(-qy2[1], c.y, fmaf(-qz2[1], c.z, wf))));
    m2 = fminf(m2, fmaf(-qx2[2], c.x, fmaf(-qy2[2], c.y, fmaf(-qz2[2], c.z, wf))));
    m3 = fminf(m3, fmaf(-qx2[3], c.x, fmaf(-qy2[3], c.y, fmaf(-qz2[3], c.z, wf))));
  }
  // bound = 17th smallest lane-min + slack (e2-space)
  float ub[4];
  float mv[4] = {m0, m1, m2, m3};
#pragma unroll
  for (int qq = 0; qq < 4; ++qq) {
    float v = mv[qq];
#pragma unroll
    for (int k = 2; k <= 64; k <<= 1) {
#pragma unroll
      for (int jj = k >> 1; jj >= 1; jj >>= 1) {
        float o = __shfl_xor(v, jj);
        bool amHigh = (lane & jj) != 0;
        bool up = (lane & k) != 0;
        bool gt = v > o;
        bool take = (amHigh ? !gt : gt) ^ up;
        v = take ? o : v;
      }
    }
    ub[qq] = __shfl(v, 16) + 1e-3f;
  }

  // pass B: gather indices with e2 <= ub (self gathered, excluded in C)
#pragma unroll 2
  for (int it = 0; it < 64; ++it) {
    int j = (it << 6) + lane;
    f3 c = *(const f3*)(cb + (size_t)j * 3);
    float wf = fmaf(c.x, c.x, fmaf(c.y, c.y, c.z * c.z));
#pragma unroll
    for (int qq = 0; qq < 4; ++qq) {
      float e = fmaf(-qx2[qq], c.x,
                     fmaf(-qy2[qq], c.y, fmaf(-qz2[qq], c.z, wf)));
      if (e <= ub[qq]) {
        unsigned pos = atomicAdd(&scnt[wave][qq], 1u);
        if (pos < 64u) cbuf[wave][qq][pos] = (unsigned)j;
      }
    }
  }
  __asm__ volatile("s_waitcnt lgkmcnt(0)" ::: "memory");

  // pass C: exact recompute, self-exclude, lex sort (adaptive)
#pragma unroll
  for (int qq = 0; qq < 4; ++qq) {
    unsigned m = scnt[wave][qq];
    m = m < 64u ? m : 64u;
    bool valid = lane < (int)m;
    unsigned ji = valid ? cbuf[wave][qq][lane] : 0u;
    if (valid && ji == (unsigned)(qbase + qq)) valid = false;
    f3 c = *(const f3*)(cb + (size_t)ji * 3);
    float dC = 1e30f;
    int iC = 0x7fffffff;
    if (valid) {
      float cw = __fadd_rn(__fadd_rn(__fmul_rn(c.x, c.x), __fmul_rn(c.y, c.y)),
                           __fmul_rn(c.z, c.z));
      float dot = __fadd_rn(
          __fadd_rn(__fmul_rn(qx[qq], c.x), __fmul_rn(qy[qq], c.y)),
          __fmul_rn(qz[qq], c.z));
      dC = __fadd_rn(__fadd_rn(qwE[qq], cw), __fmul_rn(-2.0f, dot));
      iC = (int)ji;
    }
#define SORT_STAGE(KV)                                              \
  {                                                                 \
    const int k = (KV);                                             \
    for (int jj = k >> 1; jj >= 1; jj >>= 1) {                      \
      float od = __shfl_xor(dC, jj);                                \
      int oi = __shfl_xor(iC, jj);                                  \
      bool amHigh = (lane & jj) != 0;                               \
      bool up = (lane & k) != 0;                                    \
      bool gt = (dC > od) || (dC == od && iC > oi);                 \
      bool take = (amHigh ? !gt : gt) ^ up;                         \
      dC = take ? od : dC;                                          \
      iC = take ? oi : iC;                                          \
    }                                                               \
  }
    if (m <= 32u) {
      SORT_STAGE(2) SORT_STAGE(4) SORT_STAGE(8) SORT_STAGE(16) SORT_STAGE(32)
    } else {
      SORT_STAGE(2) SORT_STAGE(4) SORT_STAGE(8) SORT_STAGE(16) SORT_STAGE(32)
      SORT_STAGE(64)
    }
#undef SORT_STAGE
    if (lane < KN)
      idx[((size_t)b * K_ + (qbase + qq)) * KN + lane] = iC;
  }
}

// ---------------------------------------------------------------------------
// Kernel 2: MFMA GEMM  SN_bf16[32768,512] = A_bf16[32768,128] @ WcatT^T
// 128x128 tile, 4 waves. batch = blockIdx&7 -> batch b L2-resident on XCD b.
// Epilogue repacks through LDS for coalesced dwordx4 stores.
// ---------------------------------------------------------------------------
__global__ __launch_bounds__(256) void k_gemm_mfma(
    const unsigned short* __restrict__ A, const unsigned short* __restrict__ BT,
    unsigned short* __restrict__ SN) {
  __shared__ char lB[32768];
  int bb = blockIdx.x & 7;
  int rest = blockIdx.x >> 3;
  int mbl = rest >> 2, nb = rest & 3;
  int m0 = bb * 4096 + mbl * 128, n0 = nb * 128;
  int t = threadIdx.x;
  {
    const char* src = (const char*)(BT + (size_t)n0 * 128);
#pragma unroll
    for (int i = 0; i < 8; ++i) {
      int byte = (t + i * 256) * 16;
      int n = byte >> 8;
      int sb = byte ^ ((n & 7) << 4);
      *(float4*)(lB + sb) = *(const float4*)(src + byte);
    }
  }
  __syncthreads();
  int wave = t >> 6, lane = t & 63;
  int wr = wave >> 1, wc = wave & 1;
  int lm = lane & 15, lk = lane >> 4;
  f32x4 z = {0.f, 0.f, 0.f, 0.f};
  f32x4 acc00 = z, acc01 = z, acc02 = z, acc03 = z;
  f32x4 acc10 = z, acc11 = z, acc12 = z, acc13 = z;
  f32x4 acc20 = z, acc21 = z, acc22 = z, acc23 = z;
  f32x4 acc30 = z, acc31 = z, acc32 = z, acc33 = z;
  const char* abase =
      (const char*)A + (size_t)(m0 + wr * 64 + lm) * 256 + lk * 16;
#pragma unroll
  for (int ks = 0; ks < 4; ++ks) {
    bf16x8 af[4], bfr[4];
#pragma unroll
    for (int mt = 0; mt < 4; ++mt)
      af[mt] = *(const bf16x8*)(abase + (size_t)mt * 4096 + ks * 64);
#pragma unroll
    for (int nt = 0; nt < 4; ++nt) {
      int n_local = wc * 64 + nt * 16 + lm;
      int byte = n_local * 256 + ks * 64 + lk * 16;
      byte ^= (n_local & 7) << 4;
      bfr[nt] = *(const bf16x8*)(lB + byte);
    }
    acc00 = __builtin_amdgcn_mfma_f32_16x16x32_bf16(af[0], bfr[0], acc00, 0, 0, 0);
    acc01 = __builtin_amdgcn_mfma_f32_16x16x32_bf16(af[0], bfr[1], acc01, 0, 0, 0);
    acc02 = __builtin_amdgcn_mfma_f32_16x16x32_bf16(af[0], bfr[2], acc02, 0, 0, 0);
    acc03 = __builtin_amdgcn_mfma_f32_16x16x32_bf16(af[0], bfr[3], acc03, 0, 0, 0);
    acc10 = __builtin_amdgcn_mfma_f32_16x16x32_bf16(af[1], bfr[0], acc10, 0, 0, 0);
    acc11 = __builtin_amdgcn_mfma_f32_16x16x32_bf16(af[1], bfr[1], acc11, 0, 0, 0);
    acc12 = __builtin_amdgcn_mfma_f32_16x16x32_bf16(af[1], bfr[2], acc12, 0, 0, 0);
    acc13 = __builtin_amdgcn_mfma_f32_16x16x32_bf16(af[1], bfr[3], acc13, 0, 0, 0);
    acc20 = __builtin_amdgcn_mfma_f32_16x16x32_bf16(af[2], bfr[0], acc20, 0, 0, 0);
    acc21 = __builtin_amdgcn_mfma_f32_16x16x32_bf16(af[2], bfr[1], acc21, 0, 0, 0);
    acc22 = __builtin_amdgcn_mfma_f32_16x16x32_bf16(af[2], bfr[2], acc22, 0, 0, 0);
    acc23 = __builtin_amdgcn_mfma_f32_16x16x32_bf16(af[2], bfr[3], acc23, 0, 0, 0);
    acc30 = __builtin_amdgcn_mfma_f32_16x16x32_bf16(af[3], bfr[0], acc30, 0, 0, 0);
    acc31 = __builtin_amdgcn_mfma_f32_16x16x32_bf16(af[3], bfr[1], acc31, 0, 0, 0);
    acc32 = __builtin_amdgcn_mfma_f32_16x16x32_bf16(af[3], bfr[2], acc32, 0, 0, 0);
    acc33 = __builtin_amdgcn_mfma_f32_16x16x32_bf16(af[3], bfr[3], acc33, 0, 0, 0);
  }
  f32x4 accs[4][4] = {{acc00, acc01, acc02, acc03},
                      {acc10, acc11, acc12, acc13},
                      {acc20, acc21, acc22, acc23},
                      {acc30, acc31, acc32, acc33}};
  __syncthreads();  // all waves done reading lB
  unsigned short* lC = (unsigned short*)lB;
#pragma unroll
  for (int mt = 0; mt < 4; ++mt) {
#pragma unroll
    for (int nt = 0; nt < 4; ++nt) {
#pragma unroll
      for (int r = 0; r < 4; ++r) {
        int row = wr * 64 + mt * 16 + lk * 4 + r;
        int col = wc * 64 + nt * 16 + lm;
        lC[row * 128 + col] = f2bf(accs[mt][nt][r]);
      }
    }
  }
  __syncthreads();
  {
    unsigned short* dst = SN + (size_t)m0 * 512 + n0;
#pragma unroll
    for (int i = 0; i < 8; ++i) {
      int e = (t + i * 256) * 8;  // element offset, 8 bf16 = 16B
      int row = e >> 7;
      int col = e & 127;
      *(f32x4*)(dst + (size_t)row * 512 + col) = *(const f32x4*)(lC + e);
    }
  }
}

// ---------------------------------------------------------------------------
// Kernel 3: attention aggregate. Wave per point; lane (g=lane>>4, r=lane&15)
// handles channels [8r,8r+8) of neighbors {g,4+g,8+g,12+g}.
// ---------------------------------------------------------------------------
__global__ __launch_bounds__(256) void k_attn(
    const unsigned short* __restrict__ SN, const int* __restrict__ idx,
    const float* __restrict__ b_a1, const float* __restrict__ b_f1,
    const float* __restrict__ W_a2, const float* __restrict__ b_a2,
    float* __restrict__ out) {
  int wave = threadIdx.x >> 6, lane = threadIdx.x & 63;
  int g = lane >> 4, r = lane & 15;
  int b = blockIdx.x & 7;
  int w = blockIdx.x >> 3;  // 0..1023
  size_t gpt = (size_t)b * K_ + w * 4 + wave;
  const unsigned short* sr = SN + gpt * 512;
  bf16x8 sa8 = *(const bf16x8*)(sr + 8 * r);
  bf16x8 sf8 = *(const bf16x8*)(sr + 128 + 8 * r);
  float4 bav0 = *(const float4*)(b_a1 + 8 * r);
  float4 bav1 = *(const float4*)(b_a1 + 8 * r + 4);
  float4 bfv0 = *(const float4*)(b_f1 + 8 * r);
  float4 bfv1 = *(const float4*)(b_f1 + 8 * r + 4);
  float4 w2v0 = *(const float4*)(W_a2 + 8 * r);
  float4 w2v1 = *(const float4*)(W_a2 + 8 * r + 4);
  float sab[8], sfb[8], w2v[8];
  {
    float bav[8] = {bav0.x, bav0.y, bav0.z, bav0.w, bav1.x, bav1.y, bav1.z, bav1.w};
    float bfv[8] = {bfv0.x, bfv0.y, bfv0.z, bfv0.w, bfv1.x, bfv1.y, bfv1.z, bfv1.w};
    float wv[8] = {w2v0.x, w2v0.y, w2v0.z, w2v0.w, w2v1.x, w2v1.y, w2v1.z, w2v1.w};
#pragma unroll
    for (int i = 0; i < 8; ++i) {
      sab[i] = bf2f((unsigned short)sa8[i]) + bav[i];
      sfb[i] = bf2f((unsigned short)sf8[i]) + bfv[i];
      w2v[i] = wv[i];
    }
  }
  float ba2v = b_a2[0];
  int nv = 0;
  if (lane < 16) nv = idx[gpt * 16 + lane];
  float lgl[4];
  float tsv[4][8];
#pragma unroll
  for (int round = 0; round < 4; ++round) {
    int n = __shfl(nv, round * 4 + g);
    const unsigned short* nr =
        SN + ((size_t)b * K_ + n) * 512 + 256 + 16 * r;
    bf16x8 u0 = *(const bf16x8*)(nr);
    bf16x8 u1 = *(const bf16x8*)(nr + 8);
    float dot = 0.0f;
#pragma unroll
    for (int i = 0; i < 4; ++i) {
      float h = sab[i] + bf2f((unsigned short)u0[2 * i]);
      h = h >= 0.0f ? h : 0.2f * h;
      float tv = sfb[i] + bf2f((unsigned short)u0[2 * i + 1]);
      tv = tv >= 0.0f ? tv : 0.2f * tv;
      dot = fmaf(h, w2v[i], dot);
      tsv[round][i] = tv;
    }
#pragma unroll
    for (int i = 0; i < 4; ++i) {
      float h = sab[4 + i] + bf2f((unsigned short)u1[2 * i]);
      h = h >= 0.0f ? h : 0.2f * h;
      float tv = sfb[4 + i] + bf2f((unsigned short)u1[2 * i + 1]);
      tv = tv >= 0.0f ? tv : 0.2f * tv;
      dot = fmaf(h, w2v[4 + i], dot);
      tsv[round][4 + i] = tv;
    }
#pragma unroll
    for (int o = 1; o < 16; o <<= 1) dot += __shfl_xor(dot, o);
    lgl[round] = dot + ba2v;
  }
  float mx = fmaxf(fmaxf(lgl[0], lgl[1]), fmaxf(lgl[2], lgl[3]));
  mx = fmaxf(mx, __shfl_xor(mx, 16));
  mx = fmaxf(mx, __shfl_xor(mx, 32));
  float e[4];
  float s = 0.0f;
#pragma unroll
  for (int round = 0; round < 4; ++round) {
    e[round] = expf(lgl[round] - mx);
    s += e[round];
  }
  s += __shfl_xor(s, 16);
  s += __shfl_xor(s, 32);
  float inv = 1.0f / s;
  float o8[8] = {0, 0, 0, 0, 0, 0, 0, 0};
#pragma unroll
  for (int round = 0; round < 4; ++round) {
    float a = e[round] * inv;
#pragma unroll
    for (int i = 0; i < 8; ++i) o8[i] = fmaf(a, tsv[round][i], o8[i]);
  }
#pragma unroll
  for (int i = 0; i < 8; ++i) {
    o8[i] += __shfl_xor(o8[i], 16);
    o8[i] += __shfl_xor(o8[i], 32);
  }
  if (g == 0) {
    float* op = out + gpt * 128 + 8 * r;
    *(float4*)op = make_float4(o8[0], o8[1], o8[2], o8[3]);
    *(float4*)(op + 4) = make_float4(o8[4], o8[5], o8[6], o8[7]);
  }
}

// ---------------------------------------------------------------------------
extern "C" void kernel_launch(void* const* d_in, const int* in_sizes, int n_in,
                              void* d_out, int out_size, void* d_ws,
                              size_t ws_size, hipStream_t stream) {
  const float* x = (const float*)d_in[0];
  const float* pos = (const float*)d_in[1];
  const float* coords = (const float*)d_in[2];
  const float* gamma = (const float*)d_in[3];
  const float* beta = (const float*)d_in[4];
  const float* Wa1 = (const float*)d_in[5];
  const float* ba1 = (const float*)d_in[6];
  const float* Wa2 = (const float*)d_in[7];
  const float* ba2 = (const float*)d_in[8];
  const float* Wf1 = (const float*)d_in[9];
  const float* bf1 = (const float*)d_in[10];
  float* out = (float*)d_out;

  char* ws = (char*)d_ws;
  unsigned short* A = (unsigned short*)ws;                                // 8MB
  unsigned short* SN = (unsigned short*)(ws + (size_t)16 * 1024 * 1024);  // 32MB
  unsigned short* WT = (unsigned short*)(ws + (size_t)80 * 1024 * 1024);  // 128KB
  int* idx = (int*)(ws + (size_t)80 * 1024 * 1024 + 512 * 1024);          // 2MB

  k_knnpre<<<6400, 256, 0, stream>>>(coords, idx, x, pos, gamma, beta, Wa1,
                                     Wf1, A, WT);
  k_gemm_mfma<<<1024, 256, 0, stream>>>(A, WT, SN);
  k_attn<<<8192, 256, 0, stream>>>(SN, idx, ba1, bf1, Wa2, ba2, out);
}